// Round 1
// baseline (324.621 us; speedup 1.0000x reference)
//
#include <hip/hip_runtime.h>

#define BB 64
#define CC 3
#define HH 512
#define WW 512

__global__ __launch_bounds__(64) void warp_precompute(
    const float* __restrict__ rot, const float* __restrict__ trans,
    const float* __restrict__ scale, float* __restrict__ ws)
{
    int b = threadIdx.x;
    if (b < BB) {
        float r = rot[b];
        float inv_s = 1.0f / scale[b];
        ws[b * 4 + 0] = cosf(r) * inv_s;
        ws[b * 4 + 1] = sinf(r) * inv_s;
        ws[b * 4 + 2] = trans[b * 2 + 0];
        ws[b * 4 + 3] = trans[b * 2 + 1];
    }
}

__global__ __launch_bounds__(256) void warp_bilinear(
    const float* __restrict__ img, const float* __restrict__ prm,
    float* __restrict__ out)
{
    const int b   = blockIdx.y;                      // wave-uniform
    const int rem = blockIdx.x * 256 + threadIdx.x;  // y*W + x within image
    const int y   = rem >> 9;                        // W = 512
    const int x   = rem & (WW - 1);

    const float4 p = *reinterpret_cast<const float4*>(prm + b * 4);
    const float cs = p.x, sn = p.y, tx = p.z, ty = p.w;

    // normalized grid coords (match reference arithmetic exactly, f32)
    const float gx = (2.0f * (float)x + 1.0f) * (1.0f / (float)WW) - 1.0f;
    const float gy = (2.0f * (float)y + 1.0f) * (1.0f / (float)HH) - 1.0f;
    const float gxt = cs * gx - sn * gy + tx;
    const float gyt = sn * gx + cs * gy + ty;
    const float ix = ((gxt + 1.0f) * (float)WW - 1.0f) * 0.5f;
    const float iy = ((gyt + 1.0f) * (float)HH - 1.0f) * 0.5f;

    const float x0f = floorf(ix);
    const float y0f = floorf(iy);
    const float wx1 = ix - x0f;
    const float wy1 = iy - y0f;
    const int x0 = (int)x0f;
    const int y0 = (int)y0f;
    const int x1 = x0 + 1;
    const int y1 = y0 + 1;

    // validity masks (zero padding) + clipped indices for the load
    const float vx0 = (x0 >= 0 && x0 < WW) ? 1.0f : 0.0f;
    const float vx1 = (x1 >= 0 && x1 < WW) ? 1.0f : 0.0f;
    const float vy0 = (y0 >= 0 && y0 < HH) ? 1.0f : 0.0f;
    const float vy1 = (y1 >= 0 && y1 < HH) ? 1.0f : 0.0f;

    const int x0c = min(max(x0, 0), WW - 1);
    const int x1c = min(max(x1, 0), WW - 1);
    const int y0c = min(max(y0, 0), HH - 1);
    const int y1c = min(max(y1, 0), HH - 1);

    const float w00 = (1.0f - wy1) * (1.0f - wx1) * vy0 * vx0;
    const float w01 = (1.0f - wy1) * wx1          * vy0 * vx1;
    const float w10 = wy1          * (1.0f - wx1) * vy1 * vx0;
    const float w11 = wy1          * wx1          * vy1 * vx1;

    const long plane = (long)HH * WW;
    const float* imb = img + (long)b * CC * plane;
    const int o00 = y0c * WW + x0c;
    const int o01 = y0c * WW + x1c;
    const int o10 = y1c * WW + x0c;
    const int o11 = y1c * WW + x1c;

    float* outb = out + (long)b * CC * plane + rem;
#pragma unroll
    for (int c = 0; c < CC; ++c) {
        const float* pc = imb + (long)c * plane;
        float v = w00 * pc[o00] + w01 * pc[o01] + w10 * pc[o10] + w11 * pc[o11];
        outb[(long)c * plane] = v;
    }
}

extern "C" void kernel_launch(void* const* d_in, const int* in_sizes, int n_in,
                              void* d_out, int out_size, void* d_ws, size_t ws_size,
                              hipStream_t stream) {
    const float* img   = (const float*)d_in[0];
    const float* rot   = (const float*)d_in[1];
    const float* trans = (const float*)d_in[2];
    const float* scale = (const float*)d_in[3];
    float* out = (float*)d_out;
    float* ws  = (float*)d_ws;

    warp_precompute<<<1, 64, 0, stream>>>(rot, trans, scale, ws);

    dim3 grid(HH * WW / 256, BB);
    warp_bilinear<<<grid, 256, 0, stream>>>(img, ws, out);
}

// Round 2
// 170.317 us; speedup vs baseline: 1.9060x; 1.9060x over previous
//
#include <hip/hip_runtime.h>

#define BB 64
#define CC 3
#define HH 512
#define WW 512
#define TILE 32
#define MAXB 48
#define LSTR 49   // padded LDS stride (odd -> spreads banks)

__global__ __launch_bounds__(64) void warp_precompute(
    const float* __restrict__ rot, const float* __restrict__ trans,
    const float* __restrict__ scale, float* __restrict__ ws)
{
    int b = threadIdx.x;
    if (b < BB) {
        float r = rot[b];
        float inv_s = 1.0f / scale[b];
        ws[b * 4 + 0] = cosf(r) * inv_s;
        ws[b * 4 + 1] = sinf(r) * inv_s;
        ws[b * 4 + 2] = trans[b * 2 + 0];
        ws[b * 4 + 3] = trans[b * 2 + 1];
    }
}

// identical float arithmetic everywhere (bbox corners AND per-pixel)
__device__ __forceinline__ void pix2in(float x, float y,
                                       float cs, float sn, float tx, float ty,
                                       float& ix, float& iy)
{
    float gx = (2.0f * x + 1.0f) * (1.0f / (float)WW) - 1.0f;
    float gy = (2.0f * y + 1.0f) * (1.0f / (float)HH) - 1.0f;
    float gxt = cs * gx - sn * gy + tx;
    float gyt = sn * gx + cs * gy + ty;
    ix = ((gxt + 1.0f) * (float)WW - 1.0f) * 0.5f;
    iy = ((gyt + 1.0f) * (float)HH - 1.0f) * 0.5f;
}

__global__ __launch_bounds__(256) void warp_tiled(
    const float* __restrict__ img, const float* __restrict__ prm,
    float* __restrict__ out)
{
    __shared__ float lds[CC][MAXB][LSTR];

    // XCD chunk swizzle: each XCD gets 2048 consecutive logical blocks = 8 whole batches
    const int g   = blockIdx.x;
    const int swz = (g & 7) * ((BB * 256) / 8) + (g >> 3);
    const int b   = swz >> 8;          // batch
    const int t   = swz & 255;         // tile id within image (16x16 tiles)
    const int oy0 = (t >> 4) * TILE;
    const int ox0 = (t & 15) * TILE;

    const float4 p = *reinterpret_cast<const float4*>(prm + b * 4);
    const float cs = p.x, sn = p.y, tpx = p.z, tpy = p.w;

    // bbox from the 4 tile corners (affine -> extremes at corners), +-1 margin
    float ixa, iya, ixb, iyb, ixc, iyc, ixd, iyd;
    pix2in((float)ox0,            (float)oy0,            cs, sn, tpx, tpy, ixa, iya);
    pix2in((float)(ox0 + TILE-1), (float)oy0,            cs, sn, tpx, tpy, ixb, iyb);
    pix2in((float)ox0,            (float)(oy0 + TILE-1), cs, sn, tpx, tpy, ixc, iyc);
    pix2in((float)(ox0 + TILE-1), (float)(oy0 + TILE-1), cs, sn, tpx, tpy, ixd, iyd);
    const float minix = fminf(fminf(ixa, ixb), fminf(ixc, ixd));
    const float maxix = fmaxf(fmaxf(ixa, ixb), fmaxf(ixc, ixd));
    const float miniy = fminf(fminf(iya, iyb), fminf(iyc, iyd));
    const float maxiy = fmaxf(fmaxf(iya, iyb), fmaxf(iyc, iyd));
    const int bx0 = (int)floorf(minix) - 1;
    const int bx1 = (int)floorf(maxix) + 2;
    const int by0 = (int)floorf(miniy) - 1;
    const int by1 = (int)floorf(maxiy) + 2;
    const int bw = bx1 - bx0 + 1;
    const int bh = by1 - by0 + 1;

    const long plane = (long)HH * WW;
    const float* imb = img + (long)b * CC * plane;
    float* outb      = out + (long)b * CC * plane;
    const int tid = threadIdx.x;

    if (bw <= MAXB && bh <= MAXB) {      // block-uniform
        // ---- stage bbox into LDS, coalesced rows; OOB -> 0 ----
        const int lane = tid & 63;
        const int wrow = tid >> 6;       // 0..3
        #pragma unroll
        for (int c = 0; c < CC; ++c) {
            const float* pc = imb + (long)c * plane;
            for (int r = wrow; r < bh; r += 4) {
                if (lane < bw) {
                    const int grow = by0 + r;
                    const int gcol = bx0 + lane;
                    float v = 0.0f;
                    if (grow >= 0 && grow < HH && gcol >= 0 && gcol < WW)
                        v = pc[grow * WW + gcol];
                    lds[c][r][lane] = v;
                }
            }
        }
        __syncthreads();

        // ---- compute 4 pixels per thread from LDS ----
        #pragma unroll
        for (int k = 0; k < 4; ++k) {
            const int pidx = tid + k * 256;
            const int py = pidx >> 5;
            const int px = pidx & 31;
            const int ox = ox0 + px, oy = oy0 + py;

            float ix, iy;
            pix2in((float)ox, (float)oy, cs, sn, tpx, tpy, ix, iy);
            const float x0f = floorf(ix), y0f = floorf(iy);
            const float wx1 = ix - x0f,  wy1 = iy - y0f;
            const int x0 = (int)x0f, y0 = (int)y0f;
            const int x1 = x0 + 1,  y1 = y0 + 1;

            const float vx0 = (x0 >= 0 && x0 < WW) ? 1.0f : 0.0f;
            const float vx1 = (x1 >= 0 && x1 < WW) ? 1.0f : 0.0f;
            const float vy0 = (y0 >= 0 && y0 < HH) ? 1.0f : 0.0f;
            const float vy1 = (y1 >= 0 && y1 < HH) ? 1.0f : 0.0f;

            const float w00 = (1.0f - wy1) * (1.0f - wx1) * vy0 * vx0;
            const float w01 = (1.0f - wy1) * wx1          * vy0 * vx1;
            const float w10 = wy1          * (1.0f - wx1) * vy1 * vx0;
            const float w11 = wy1          * wx1          * vy1 * vx1;

            const int lx0 = min(max(x0 - bx0, 0), bw - 1);
            const int lx1 = min(max(x1 - bx0, 0), bw - 1);
            const int ly0 = min(max(y0 - by0, 0), bh - 1);
            const int ly1 = min(max(y1 - by0, 0), bh - 1);

            const int ob = oy * WW + ox;
            #pragma unroll
            for (int c = 0; c < CC; ++c) {
                const float v = w00 * lds[c][ly0][lx0] + w01 * lds[c][ly0][lx1]
                              + w10 * lds[c][ly1][lx0] + w11 * lds[c][ly1][lx1];
                __builtin_nontemporal_store(v, &outb[(long)c * plane + ob]);
            }
        }
    } else {
        // ---- fallback: direct global gather (block-uniform branch) ----
        #pragma unroll
        for (int k = 0; k < 4; ++k) {
            const int pidx = tid + k * 256;
            const int py = pidx >> 5;
            const int px = pidx & 31;
            const int ox = ox0 + px, oy = oy0 + py;

            float ix, iy;
            pix2in((float)ox, (float)oy, cs, sn, tpx, tpy, ix, iy);
            const float x0f = floorf(ix), y0f = floorf(iy);
            const float wx1 = ix - x0f,  wy1 = iy - y0f;
            const int x0 = (int)x0f, y0 = (int)y0f;
            const int x1 = x0 + 1,  y1 = y0 + 1;

            const float vx0 = (x0 >= 0 && x0 < WW) ? 1.0f : 0.0f;
            const float vx1 = (x1 >= 0 && x1 < WW) ? 1.0f : 0.0f;
            const float vy0 = (y0 >= 0 && y0 < HH) ? 1.0f : 0.0f;
            const float vy1 = (y1 >= 0 && y1 < HH) ? 1.0f : 0.0f;

            const int x0c = min(max(x0, 0), WW - 1);
            const int x1c = min(max(x1, 0), WW - 1);
            const int y0c = min(max(y0, 0), HH - 1);
            const int y1c = min(max(y1, 0), HH - 1);

            const float w00 = (1.0f - wy1) * (1.0f - wx1) * vy0 * vx0;
            const float w01 = (1.0f - wy1) * wx1          * vy0 * vx1;
            const float w10 = wy1          * (1.0f - wx1) * vy1 * vx0;
            const float w11 = wy1          * wx1          * vy1 * vx1;

            const int o00 = y0c * WW + x0c, o01 = y0c * WW + x1c;
            const int o10 = y1c * WW + x0c, o11 = y1c * WW + x1c;
            const int ob = oy * WW + ox;
            #pragma unroll
            for (int c = 0; c < CC; ++c) {
                const float* pc = imb + (long)c * plane;
                const float v = w00 * pc[o00] + w01 * pc[o01]
                              + w10 * pc[o10] + w11 * pc[o11];
                __builtin_nontemporal_store(v, &outb[(long)c * plane + ob]);
            }
        }
    }
}

extern "C" void kernel_launch(void* const* d_in, const int* in_sizes, int n_in,
                              void* d_out, int out_size, void* d_ws, size_t ws_size,
                              hipStream_t stream) {
    const float* img   = (const float*)d_in[0];
    const float* rot   = (const float*)d_in[1];
    const float* trans = (const float*)d_in[2];
    const float* scale = (const float*)d_in[3];
    float* out = (float*)d_out;
    float* ws  = (float*)d_ws;

    warp_precompute<<<1, 64, 0, stream>>>(rot, trans, scale, ws);

    warp_tiled<<<dim3(BB * 256), 256, 0, stream>>>(img, ws, out);
}

// Round 4
// 85.213 us; speedup vs baseline: 3.8095x; 1.9987x over previous
//
#include <hip/hip_runtime.h>

#define BB 64
#define CC 3
#define HH 512
#define WW 512
#define TILE 32
#define MAXBH 48
#define MAXBW 52
#define LSTR 53   // odd dword stride -> conflict-light reads

typedef float f32x4 __attribute__((ext_vector_type(4)));

__global__ __launch_bounds__(64) void warp_precompute(
    const float* __restrict__ rot, const float* __restrict__ trans,
    const float* __restrict__ scale, float* __restrict__ ws)
{
    int b = threadIdx.x;
    if (b < BB) {
        float r = rot[b];
        float inv_s = 1.0f / scale[b];
        ws[b * 4 + 0] = cosf(r) * inv_s;
        ws[b * 4 + 1] = sinf(r) * inv_s;
        ws[b * 4 + 2] = trans[b * 2 + 0];
        ws[b * 4 + 3] = trans[b * 2 + 1];
    }
}

__device__ __forceinline__ void pix2in(float x, float y,
                                       float cs, float sn, float tx, float ty,
                                       float& ix, float& iy)
{
    float gx = (2.0f * x + 1.0f) * (1.0f / (float)WW) - 1.0f;
    float gy = (2.0f * y + 1.0f) * (1.0f / (float)HH) - 1.0f;
    float gxt = cs * gx - sn * gy + tx;
    float gyt = sn * gx + cs * gy + ty;
    ix = ((gxt + 1.0f) * (float)WW - 1.0f) * 0.5f;
    iy = ((gyt + 1.0f) * (float)HH - 1.0f) * 0.5f;
}

__global__ __launch_bounds__(256) void warp_tiled(
    const float* __restrict__ img, const float* __restrict__ prm,
    float* __restrict__ out)
{
    __shared__ float lds[CC][MAXBH][LSTR];

    // XCD chunk swizzle: each XCD owns 8 whole batches
    const int g   = blockIdx.x;
    const int swz = (g & 7) * ((BB * 256) / 8) + (g >> 3);
    const int b   = swz >> 8;
    const int t   = swz & 255;
    const int oy0 = (t >> 4) * TILE;
    const int ox0 = (t & 15) * TILE;

    const float4 p = *reinterpret_cast<const float4*>(prm + b * 4);
    const float cs = p.x, sn = p.y, tpx = p.z, tpy = p.w;

    float ixa, iya, ixb, iyb, ixc, iyc, ixd, iyd;
    pix2in((float)ox0,              (float)oy0,              cs, sn, tpx, tpy, ixa, iya);
    pix2in((float)(ox0 + TILE - 1), (float)oy0,              cs, sn, tpx, tpy, ixb, iyb);
    pix2in((float)ox0,              (float)(oy0 + TILE - 1), cs, sn, tpx, tpy, ixc, iyc);
    pix2in((float)(ox0 + TILE - 1), (float)(oy0 + TILE - 1), cs, sn, tpx, tpy, ixd, iyd);
    const float minix = fminf(fminf(ixa, ixb), fminf(ixc, ixd));
    const float maxix = fmaxf(fmaxf(ixa, ixb), fmaxf(ixc, ixd));
    const float miniy = fminf(fminf(iya, iyb), fminf(iyc, iyd));
    const float maxiy = fmaxf(fmaxf(iya, iyb), fmaxf(iyc, iyd));
    const int bx0  = (int)floorf(minix) - 1;
    const int bx1  = (int)floorf(maxix) + 2;
    const int by0  = (int)floorf(miniy) - 1;
    const int by1  = (int)floorf(maxiy) + 2;
    const int bx0c = bx0 & ~3;            // align left edge for float4 loads
    const int bw   = bx1 - bx0c + 1;
    const int bh   = by1 - by0 + 1;

    const long plane = (long)HH * WW;
    const float* imb = img + (long)b * CC * plane;
    float* outb      = out + (long)b * CC * plane;
    const int tid = threadIdx.x;

    if (bw <= MAXBW && bh <= MAXBH) {     // block-uniform (always true for scale=1)
        // ---- stage: quarter-wave rows of float4 ----
        const int q  = tid >> 4;          // 0..15
        const int ql = tid & 15;          // 13 active lanes cover 52 cols
        #pragma unroll
        for (int c = 0; c < CC; ++c) {
            const float* pc = imb + (long)c * plane;
            for (int r = q; r < bh; r += 16) {
                if (ql < 13) {
                    const int grow = by0 + r;
                    const int gcol = bx0c + ql * 4;
                    float4 v = make_float4(0.f, 0.f, 0.f, 0.f);
                    if (grow >= 0 && grow < HH) {
                        const float* prow = pc + (long)grow * WW;
                        if (gcol >= 0 && gcol <= WW - 4) {
                            v = *reinterpret_cast<const float4*>(prow + gcol);
                        } else {                       // image-edge float4 (rare)
                            int gc0 = gcol + 0, gc1 = gcol + 1, gc2 = gcol + 2, gc3 = gcol + 3;
                            v.x = (gc0 >= 0 && gc0 < WW) ? prow[gc0] : 0.f;
                            v.y = (gc1 >= 0 && gc1 < WW) ? prow[gc1] : 0.f;
                            v.z = (gc2 >= 0 && gc2 < WW) ? prow[gc2] : 0.f;
                            v.w = (gc3 >= 0 && gc3 < WW) ? prow[gc3] : 0.f;
                        }
                    }
                    float* dst = &lds[c][r][ql * 4];
                    dst[0] = v.x; dst[1] = v.y; dst[2] = v.z; dst[3] = v.w;
                }
            }
        }
        __syncthreads();

        // ---- compute: 4-px horizontal strip per thread ----
        const int row = tid >> 3;          // 0..31
        const int xq  = (tid & 7) * 4;     // 0,4,...,28
        const int oy  = oy0 + row;
        const int oxb = ox0 + xq;

        float ix0, iy0;
        pix2in((float)oxb, (float)oy, cs, sn, tpx, tpy, ix0, iy0);

        f32x4 res[CC];
        #pragma unroll
        for (int e = 0; e < 4; ++e) {
            const float ix = fmaf((float)e, cs, ix0);   // affine: ix steps by cs per x
            const float iy = fmaf((float)e, sn, iy0);
            const float x0f = floorf(ix), y0f = floorf(iy);
            const float wx1 = ix - x0f,  wy1 = iy - y0f;
            const int x0 = (int)x0f, y0 = (int)y0f;
            const int x1 = x0 + 1,  y1 = y0 + 1;

            const float vx0 = (x0 >= 0 && x0 < WW) ? 1.0f : 0.0f;
            const float vx1 = (x1 >= 0 && x1 < WW) ? 1.0f : 0.0f;
            const float vy0 = (y0 >= 0 && y0 < HH) ? 1.0f : 0.0f;
            const float vy1 = (y1 >= 0 && y1 < HH) ? 1.0f : 0.0f;

            const float w00 = (1.0f - wy1) * (1.0f - wx1) * vy0 * vx0;
            const float w01 = (1.0f - wy1) * wx1          * vy0 * vx1;
            const float w10 = wy1          * (1.0f - wx1) * vy1 * vx0;
            const float w11 = wy1          * wx1          * vy1 * vx1;

            const int idx = (y0 - by0) * LSTR + (x0 - bx0c);   // no clamps needed
            #pragma unroll
            for (int c = 0; c < CC; ++c) {
                const float* pb = &lds[c][0][0] + idx;
                const float v = w00 * pb[0] + w01 * pb[1]
                              + w10 * pb[LSTR] + w11 * pb[LSTR + 1];
                res[c][e] = v;
            }
        }
        const long ob = (long)oy * WW + oxb;
        #pragma unroll
        for (int c = 0; c < CC; ++c)
            __builtin_nontemporal_store(res[c],
                reinterpret_cast<f32x4*>(outb + (long)c * plane + ob));
    } else {
        // ---- fallback: direct global gather (never taken for scale=1) ----
        #pragma unroll
        for (int k = 0; k < 4; ++k) {
            const int pidx = tid + k * 256;
            const int py = pidx >> 5;
            const int px = pidx & 31;
            const int ox = ox0 + px, oy = oy0 + py;

            float ix, iy;
            pix2in((float)ox, (float)oy, cs, sn, tpx, tpy, ix, iy);
            const float x0f = floorf(ix), y0f = floorf(iy);
            const float wx1 = ix - x0f,  wy1 = iy - y0f;
            const int x0 = (int)x0f, y0 = (int)y0f;
            const int x1 = x0 + 1,  y1 = y0 + 1;

            const float vx0 = (x0 >= 0 && x0 < WW) ? 1.0f : 0.0f;
            const float vx1 = (x1 >= 0 && x1 < WW) ? 1.0f : 0.0f;
            const float vy0 = (y0 >= 0 && y0 < HH) ? 1.0f : 0.0f;
            const float vy1 = (y1 >= 0 && y1 < HH) ? 1.0f : 0.0f;

            const int x0c = min(max(x0, 0), WW - 1);
            const int x1c = min(max(x1, 0), WW - 1);
            const int y0c = min(max(y0, 0), HH - 1);
            const int y1c = min(max(y1, 0), HH - 1);

            const float w00 = (1.0f - wy1) * (1.0f - wx1) * vy0 * vx0;
            const float w01 = (1.0f - wy1) * wx1          * vy0 * vx1;
            const float w10 = wy1          * (1.0f - wx1) * vy1 * vx0;
            const float w11 = wy1          * wx1          * vy1 * vx1;

            const int o00 = y0c * WW + x0c, o01 = y0c * WW + x1c;
            const int o10 = y1c * WW + x0c, o11 = y1c * WW + x1c;
            const int ob = oy * WW + ox;
            #pragma unroll
            for (int c = 0; c < CC; ++c) {
                const float* pc = imb + (long)c * plane;
                const float v = w00 * pc[o00] + w01 * pc[o01]
                              + w10 * pc[o10] + w11 * pc[o11];
                __builtin_nontemporal_store(v, &outb[(long)c * plane + ob]);
            }
        }
    }
}

extern "C" void kernel_launch(void* const* d_in, const int* in_sizes, int n_in,
                              void* d_out, int out_size, void* d_ws, size_t ws_size,
                              hipStream_t stream) {
    const float* img   = (const float*)d_in[0];
    const float* rot   = (const float*)d_in[1];
    const float* trans = (const float*)d_in[2];
    const float* scale = (const float*)d_in[3];
    float* out = (float*)d_out;
    float* ws  = (float*)d_ws;

    warp_precompute<<<1, 64, 0, stream>>>(rot, trans, scale, ws);
    warp_tiled<<<dim3(BB * 256), 256, 0, stream>>>(img, ws, out);
}

// Round 5
// 84.133 us; speedup vs baseline: 3.8584x; 1.0128x over previous
//
#include <hip/hip_runtime.h>

#define BB 64
#define CC 3
#define HH 512
#define WW 512
#define TILE 32
#define MAXBH 48
#define MAXBW 52
#define LSTR 53   // odd dword stride -> decorrelates rows across banks

typedef float f32x2 __attribute__((ext_vector_type(2)));

__global__ __launch_bounds__(64) void warp_precompute(
    const float* __restrict__ rot, const float* __restrict__ trans,
    const float* __restrict__ scale, float* __restrict__ ws)
{
    int b = threadIdx.x;
    if (b < BB) {
        float r = rot[b];
        float inv_s = 1.0f / scale[b];
        ws[b * 4 + 0] = cosf(r) * inv_s;
        ws[b * 4 + 1] = sinf(r) * inv_s;
        ws[b * 4 + 2] = trans[b * 2 + 0];
        ws[b * 4 + 3] = trans[b * 2 + 1];
    }
}

__device__ __forceinline__ void pix2in(float x, float y,
                                       float cs, float sn, float tx, float ty,
                                       float& ix, float& iy)
{
    float gx = (2.0f * x + 1.0f) * (1.0f / (float)WW) - 1.0f;
    float gy = (2.0f * y + 1.0f) * (1.0f / (float)HH) - 1.0f;
    float gxt = cs * gx - sn * gy + tx;
    float gyt = sn * gx + cs * gy + ty;
    ix = ((gxt + 1.0f) * (float)WW - 1.0f) * 0.5f;
    iy = ((gyt + 1.0f) * (float)HH - 1.0f) * 0.5f;
}

template <bool INTERIOR>
__device__ __forceinline__ void compute_store(
    const float (*lds)[MAXBH][LSTR], float* __restrict__ outb,
    int tid, int ox0, int oy0, int bx0c, int by0,
    float cs, float sn, float tpx, float tpy, long plane)
{
    const int row = tid >> 4;            // 0..31
    const int xp  = (tid & 15) * 2;      // 0,2,...,30
    const int oy  = oy0 + row;
    const int oxb = ox0 + xp;

    float ix0, iy0;
    pix2in((float)oxb, (float)oy, cs, sn, tpx, tpy, ix0, iy0);

    f32x2 res[CC];
    #pragma unroll
    for (int e = 0; e < 2; ++e) {
        const float ix = fmaf((float)e, cs, ix0);   // affine: +cs per output x
        const float iy = fmaf((float)e, sn, iy0);
        const float x0f = floorf(ix), y0f = floorf(iy);
        const float wx1 = ix - x0f,  wy1 = iy - y0f;
        const float wx0 = 1.0f - wx1, wy0 = 1.0f - wy1;
        const int x0 = (int)x0f, y0 = (int)y0f;

        float w00 = wy0 * wx0, w01 = wy0 * wx1, w10 = wy1 * wx0, w11 = wy1 * wx1;
        if (!INTERIOR) {
            const int x1 = x0 + 1, y1 = y0 + 1;
            const float vx0 = (x0 >= 0 && x0 < WW) ? 1.0f : 0.0f;
            const float vx1 = (x1 >= 0 && x1 < WW) ? 1.0f : 0.0f;
            const float vy0 = (y0 >= 0 && y0 < HH) ? 1.0f : 0.0f;
            const float vy1 = (y1 >= 0 && y1 < HH) ? 1.0f : 0.0f;
            w00 *= vy0 * vx0; w01 *= vy0 * vx1; w10 *= vy1 * vx0; w11 *= vy1 * vx1;
        }

        const int idx = (y0 - by0) * LSTR + (x0 - bx0c);   // margin guarantees in-range
        #pragma unroll
        for (int c = 0; c < CC; ++c) {
            const float* pb = &lds[c][0][0] + idx;
            res[c][e] = w00 * pb[0] + w01 * pb[1]
                      + w10 * pb[LSTR] + w11 * pb[LSTR + 1];
        }
    }
    const long ob = (long)oy * WW + oxb;
    #pragma unroll
    for (int c = 0; c < CC; ++c)
        __builtin_nontemporal_store(res[c],
            reinterpret_cast<f32x2*>(outb + (long)c * plane + ob));
}

__global__ __launch_bounds__(512) void warp_tiled(
    const float* __restrict__ img, const float* __restrict__ prm,
    float* __restrict__ out)
{
    __shared__ float lds[CC][MAXBH][LSTR];

    // XCD chunk swizzle: each XCD owns 8 whole batches
    const int g   = blockIdx.x;
    const int swz = (g & 7) * ((BB * 256) / 8) + (g >> 3);
    const int b   = swz >> 8;
    const int t   = swz & 255;
    const int oy0 = (t >> 4) * TILE;
    const int ox0 = (t & 15) * TILE;

    const float4 p = *reinterpret_cast<const float4*>(prm + b * 4);
    const float cs = p.x, sn = p.y, tpx = p.z, tpy = p.w;

    float ixa, iya, ixb, iyb, ixc, iyc, ixd, iyd;
    pix2in((float)ox0,              (float)oy0,              cs, sn, tpx, tpy, ixa, iya);
    pix2in((float)(ox0 + TILE - 1), (float)oy0,              cs, sn, tpx, tpy, ixb, iyb);
    pix2in((float)ox0,              (float)(oy0 + TILE - 1), cs, sn, tpx, tpy, ixc, iyc);
    pix2in((float)(ox0 + TILE - 1), (float)(oy0 + TILE - 1), cs, sn, tpx, tpy, ixd, iyd);
    const float minix = fminf(fminf(ixa, ixb), fminf(ixc, ixd));
    const float maxix = fmaxf(fmaxf(ixa, ixb), fmaxf(ixc, ixd));
    const float miniy = fminf(fminf(iya, iyb), fminf(iyc, iyd));
    const float maxiy = fmaxf(fmaxf(iya, iyb), fmaxf(iyc, iyd));
    const int bx0  = (int)floorf(minix) - 1;
    const int bx1  = (int)floorf(maxix) + 2;
    const int by0  = (int)floorf(miniy) - 1;
    const int by1  = (int)floorf(maxiy) + 2;
    const int bx0c = bx0 & ~3;            // align left edge for float4 loads
    const int bw   = bx1 - bx0c + 1;
    const int bh   = by1 - by0 + 1;

    const long plane = (long)HH * WW;
    const float* imb = img + (long)b * CC * plane;
    float* outb      = out + (long)b * CC * plane;
    const int tid = threadIdx.x;

    if (bw <= MAXBW && bh <= MAXBH) {     // block-uniform (always true for scale=1)
        // ---- stage: 16-lane groups load float4 rows ----
        const int q  = tid >> 4;          // 0..31
        const int ql = tid & 15;          // 13 active lanes cover 52 cols
        const bool interior = (bx0c >= 0) && (bx1 < WW) && (by0 >= 0) && (by1 < HH);
        #pragma unroll
        for (int c = 0; c < CC; ++c) {
            const float* pc = imb + (long)c * plane;
            for (int r = q; r < bh; r += 32) {
                if (ql < 13) {
                    const int grow = by0 + r;
                    const int gcol = bx0c + ql * 4;
                    float4 v = make_float4(0.f, 0.f, 0.f, 0.f);
                    if (grow >= 0 && grow < HH) {
                        const float* prow = pc + (long)grow * WW;
                        if (gcol >= 0 && gcol <= WW - 4) {
                            v = *reinterpret_cast<const float4*>(prow + gcol);
                        } else {                       // image-edge float4 (rare)
                            int gc0 = gcol, gc1 = gcol + 1, gc2 = gcol + 2, gc3 = gcol + 3;
                            v.x = (gc0 >= 0 && gc0 < WW) ? prow[gc0] : 0.f;
                            v.y = (gc1 >= 0 && gc1 < WW) ? prow[gc1] : 0.f;
                            v.z = (gc2 >= 0 && gc2 < WW) ? prow[gc2] : 0.f;
                            v.w = (gc3 >= 0 && gc3 < WW) ? prow[gc3] : 0.f;
                        }
                    }
                    float* dst = &lds[c][r][ql * 4];
                    dst[0] = v.x; dst[1] = v.y; dst[2] = v.z; dst[3] = v.w;
                }
            }
        }
        __syncthreads();

        if (interior)
            compute_store<true >(lds, outb, tid, ox0, oy0, bx0c, by0, cs, sn, tpx, tpy, plane);
        else
            compute_store<false>(lds, outb, tid, ox0, oy0, bx0c, by0, cs, sn, tpx, tpy, plane);
    } else {
        // ---- fallback: direct global gather (never taken for scale=1) ----
        #pragma unroll
        for (int k = 0; k < 2; ++k) {
            const int pidx = tid + k * 512;
            const int py = pidx >> 5;
            const int px = pidx & 31;
            const int ox = ox0 + px, oy = oy0 + py;

            float ix, iy;
            pix2in((float)ox, (float)oy, cs, sn, tpx, tpy, ix, iy);
            const float x0f = floorf(ix), y0f = floorf(iy);
            const float wx1 = ix - x0f,  wy1 = iy - y0f;
            const int x0 = (int)x0f, y0 = (int)y0f;
            const int x1 = x0 + 1,  y1 = y0 + 1;

            const float vx0 = (x0 >= 0 && x0 < WW) ? 1.0f : 0.0f;
            const float vx1 = (x1 >= 0 && x1 < WW) ? 1.0f : 0.0f;
            const float vy0 = (y0 >= 0 && y0 < HH) ? 1.0f : 0.0f;
            const float vy1 = (y1 >= 0 && y1 < HH) ? 1.0f : 0.0f;

            const int x0c = min(max(x0, 0), WW - 1);
            const int x1c = min(max(x1, 0), WW - 1);
            const int y0c = min(max(y0, 0), HH - 1);
            const int y1c = min(max(y1, 0), HH - 1);

            const float w00 = (1.0f - wy1) * (1.0f - wx1) * vy0 * vx0;
            const float w01 = (1.0f - wy1) * wx1          * vy0 * vx1;
            const float w10 = wy1          * (1.0f - wx1) * vy1 * vx0;
            const float w11 = wy1          * wx1          * vy1 * vx1;

            const int o00 = y0c * WW + x0c, o01 = y0c * WW + x1c;
            const int o10 = y1c * WW + x0c, o11 = y1c * WW + x1c;
            const int ob = oy * WW + ox;
            #pragma unroll
            for (int c = 0; c < CC; ++c) {
                const float* pc = imb + (long)c * plane;
                const float v = w00 * pc[o00] + w01 * pc[o01]
                              + w10 * pc[o10] + w11 * pc[o11];
                __builtin_nontemporal_store(v, &outb[(long)c * plane + ob]);
            }
        }
    }
}

extern "C" void kernel_launch(void* const* d_in, const int* in_sizes, int n_in,
                              void* d_out, int out_size, void* d_ws, size_t ws_size,
                              hipStream_t stream) {
    const float* img   = (const float*)d_in[0];
    const float* rot   = (const float*)d_in[1];
    const float* trans = (const float*)d_in[2];
    const float* scale = (const float*)d_in[3];
    float* out = (float*)d_out;
    float* ws  = (float*)d_ws;

    warp_precompute<<<1, 64, 0, stream>>>(rot, trans, scale, ws);
    warp_tiled<<<dim3(BB * 256), 512, 0, stream>>>(img, ws, out);
}

// Round 6
// 77.679 us; speedup vs baseline: 4.1790x; 1.0831x over previous
//
#include <hip/hip_runtime.h>
#include <stdint.h>

#define BB 64
#define CC 3
#define HH 512
#define WW 512
#define TILE 32
#define MAXBH 48
#define MAXBW 52
#define LSTR 53   // odd dword stride -> decorrelates rows across banks

typedef float f32x2 __attribute__((ext_vector_type(2)));

__device__ __forceinline__ void pix2in(float x, float y,
                                       float cs, float sn, float tx, float ty,
                                       float& ix, float& iy)
{
    float gx = (2.0f * x + 1.0f) * (1.0f / (float)WW) - 1.0f;
    float gy = (2.0f * y + 1.0f) * (1.0f / (float)HH) - 1.0f;
    float gxt = cs * gx - sn * gy + tx;
    float gyt = sn * gx + cs * gy + ty;
    ix = ((gxt + 1.0f) * (float)WW - 1.0f) * 0.5f;
    iy = ((gyt + 1.0f) * (float)HH - 1.0f) * 0.5f;
}

// ws layout: float prm[64*4] (cs,sn,tx,ty per batch), then uint32 desc[16384]
__global__ __launch_bounds__(256) void warp_setup(
    const float* __restrict__ rot, const float* __restrict__ trans,
    const float* __restrict__ scale, float* __restrict__ ws)
{
    const int i = blockIdx.x * 256 + threadIdx.x;   // 0..16383 = b*256+t
    const int b = i >> 8, t = i & 255;
    const float r = rot[b];
    const float inv_s = 1.0f / scale[b];
    const float cs = cosf(r) * inv_s;
    const float sn = sinf(r) * inv_s;
    const float tx = trans[2 * b], ty = trans[2 * b + 1];
    if (t == 0)
        reinterpret_cast<float4*>(ws)[b] = make_float4(cs, sn, tx, ty);

    const int oy0 = (t >> 4) * TILE;
    const int ox0 = (t & 15) * TILE;
    float ixa, iya, ixb, iyb, ixc, iyc, ixd, iyd;
    pix2in((float)ox0,              (float)oy0,              cs, sn, tx, ty, ixa, iya);
    pix2in((float)(ox0 + TILE - 1), (float)oy0,              cs, sn, tx, ty, ixb, iyb);
    pix2in((float)ox0,              (float)(oy0 + TILE - 1), cs, sn, tx, ty, ixc, iyc);
    pix2in((float)(ox0 + TILE - 1), (float)(oy0 + TILE - 1), cs, sn, tx, ty, ixd, iyd);
    const float minix = fminf(fminf(ixa, ixb), fminf(ixc, ixd));
    const float maxix = fmaxf(fmaxf(ixa, ixb), fmaxf(ixc, ixd));
    const float miniy = fminf(fminf(iya, iyb), fminf(iyc, iyd));
    const float maxiy = fmaxf(fmaxf(iya, iyb), fmaxf(iyc, iyd));
    const int bx0 = (int)floorf(minix) - 1;
    const int bx1 = (int)floorf(maxix) + 2;
    const int by0 = (int)floorf(miniy) - 1;
    const int by1 = (int)floorf(maxiy) + 2;
    int bx0c = bx0 & ~3;
    const int bw = bx1 - bx0c + 1;
    const int bh = by1 - by0 + 1;

    const uint32_t fit      = (bw <= MAXBW && bh <= MAXBH) ? 1u : 0u;
    const uint32_t interior = (bx0c >= 0 && bx1 < WW && by0 >= 0 && by1 < HH) ? 1u : 0u;
    const int bx0s = min(max(bx0c, -2048), 2047);
    const int by0s = min(max(by0,  -2048), 2047);
    const int bhs  = min(bh, 63);
    const uint32_t desc = ((uint32_t)bx0s & 0xFFFu)
                        | (((uint32_t)by0s & 0xFFFu) << 12)
                        | ((uint32_t)bhs << 24)
                        | (fit << 30) | (interior << 31);
    reinterpret_cast<uint32_t*>(ws)[256 + i] = desc;
}

template <bool INTERIOR>
__device__ __forceinline__ void compute_store(
    const float (*lds)[MAXBH][LSTR], float* __restrict__ outb,
    int tid, int ox0, int oy0, int bx0c, int by0,
    float cs, float sn, float tpx, float tpy, long plane)
{
    const int row = tid >> 4;            // 0..31
    const int xp  = (tid & 15) * 2;      // 0,2,...,30
    const int oy  = oy0 + row;
    const int oxb = ox0 + xp;

    float ix0, iy0;
    pix2in((float)oxb, (float)oy, cs, sn, tpx, tpy, ix0, iy0);

    f32x2 res[CC];
    #pragma unroll
    for (int e = 0; e < 2; ++e) {
        const float ix = fmaf((float)e, cs, ix0);
        const float iy = fmaf((float)e, sn, iy0);
        const float x0f = floorf(ix), y0f = floorf(iy);
        const float wx1 = ix - x0f,  wy1 = iy - y0f;
        const float wx0 = 1.0f - wx1, wy0 = 1.0f - wy1;
        const int x0 = (int)x0f, y0 = (int)y0f;

        float w00 = wy0 * wx0, w01 = wy0 * wx1, w10 = wy1 * wx0, w11 = wy1 * wx1;
        if (!INTERIOR) {
            const int x1 = x0 + 1, y1 = y0 + 1;
            const float vx0 = (x0 >= 0 && x0 < WW) ? 1.0f : 0.0f;
            const float vx1 = (x1 >= 0 && x1 < WW) ? 1.0f : 0.0f;
            const float vy0 = (y0 >= 0 && y0 < HH) ? 1.0f : 0.0f;
            const float vy1 = (y1 >= 0 && y1 < HH) ? 1.0f : 0.0f;
            w00 *= vy0 * vx0; w01 *= vy0 * vx1; w10 *= vy1 * vx0; w11 *= vy1 * vx1;
        }

        const int idx = (y0 - by0) * LSTR + (x0 - bx0c);   // margin guarantees in-range
        #pragma unroll
        for (int c = 0; c < CC; ++c) {
            const float* pb = &lds[c][0][0] + idx;
            res[c][e] = w00 * pb[0] + w01 * pb[1]
                      + w10 * pb[LSTR] + w11 * pb[LSTR + 1];
        }
    }
    const long ob = (long)oy * WW + oxb;
    #pragma unroll
    for (int c = 0; c < CC; ++c)
        __builtin_nontemporal_store(res[c],
            reinterpret_cast<f32x2*>(outb + (long)c * plane + ob));
}

__global__ __launch_bounds__(512) void warp_tiled(
    const float* __restrict__ img, const float* __restrict__ ws,
    float* __restrict__ out)
{
    __shared__ float lds[CC][MAXBH][LSTR];

    // XCD chunk swizzle: each XCD owns 8 whole batches
    const int g   = blockIdx.x;
    const int swz = (g & 7) * ((BB * 256) / 8) + (g >> 3);
    const int b   = swz >> 8;
    const int t   = swz & 255;
    const int oy0 = (t >> 4) * TILE;
    const int ox0 = (t & 15) * TILE;

    const float4 p = reinterpret_cast<const float4*>(ws)[b];        // uniform s_load
    const float cs = p.x, sn = p.y, tpx = p.z, tpy = p.w;
    const uint32_t desc = reinterpret_cast<const uint32_t*>(ws)[256 + swz];
    const int  bx0c     = ((int)(desc << 20)) >> 20;   // sext bits 0..11
    const int  by0      = ((int)(desc << 8))  >> 20;   // sext bits 12..23
    const int  bh       = (desc >> 24) & 63;
    const bool fit      = (desc >> 30) & 1;
    const bool interior = (desc >> 31) & 1;

    const long plane = (long)HH * WW;
    const float* imb = img + (long)b * CC * plane;
    float* outb      = out + (long)b * CC * plane;
    const int tid = threadIdx.x;

    if (fit) {
        const int q  = tid >> 4;          // 0..31 row group
        const int ql = tid & 15;          // 13 active lanes cover 52 cols
        if (ql < 13) {
            if (interior) {
                // no bounds checks: rows [by0,by0+bh) in image; col overreads stay in-plane
                const float* prow = imb + (long)(by0 + q) * WW + bx0c + ql * 4;
                #pragma unroll
                for (int c = 0; c < CC; ++c) {
                    const float* pr = prow + (long)c * plane;
                    if (q < bh) {
                        const float4 v = *reinterpret_cast<const float4*>(pr);
                        float* dst = &lds[c][q][ql * 4];
                        dst[0] = v.x; dst[1] = v.y; dst[2] = v.z; dst[3] = v.w;
                    }
                    if (q + 32 < bh) {
                        const float4 v = *reinterpret_cast<const float4*>(pr + 32 * WW);
                        float* dst = &lds[c][q + 32][ql * 4];
                        dst[0] = v.x; dst[1] = v.y; dst[2] = v.z; dst[3] = v.w;
                    }
                }
            } else {
                #pragma unroll
                for (int c = 0; c < CC; ++c) {
                    const float* pc = imb + (long)c * plane;
                    for (int r = q; r < bh; r += 32) {
                        const int grow = by0 + r;
                        const int gcol = bx0c + ql * 4;
                        float4 v = make_float4(0.f, 0.f, 0.f, 0.f);
                        if (grow >= 0 && grow < HH) {
                            const float* prow = pc + (long)grow * WW;
                            if (gcol >= 0 && gcol <= WW - 4) {
                                v = *reinterpret_cast<const float4*>(prow + gcol);
                            } else {
                                int gc0 = gcol, gc1 = gcol + 1, gc2 = gcol + 2, gc3 = gcol + 3;
                                v.x = (gc0 >= 0 && gc0 < WW) ? prow[gc0] : 0.f;
                                v.y = (gc1 >= 0 && gc1 < WW) ? prow[gc1] : 0.f;
                                v.z = (gc2 >= 0 && gc2 < WW) ? prow[gc2] : 0.f;
                                v.w = (gc3 >= 0 && gc3 < WW) ? prow[gc3] : 0.f;
                            }
                        }
                        float* dst = &lds[c][r][ql * 4];
                        dst[0] = v.x; dst[1] = v.y; dst[2] = v.z; dst[3] = v.w;
                    }
                }
            }
        }
        __syncthreads();

        if (interior)
            compute_store<true >(lds, outb, tid, ox0, oy0, bx0c, by0, cs, sn, tpx, tpy, plane);
        else
            compute_store<false>(lds, outb, tid, ox0, oy0, bx0c, by0, cs, sn, tpx, tpy, plane);
    } else {
        // ---- fallback: direct global gather (never taken for scale=1) ----
        #pragma unroll
        for (int k = 0; k < 2; ++k) {
            const int pidx = tid + k * 512;
            const int py = pidx >> 5;
            const int px = pidx & 31;
            const int ox = ox0 + px, oy = oy0 + py;

            float ix, iy;
            pix2in((float)ox, (float)oy, cs, sn, tpx, tpy, ix, iy);
            const float x0f = floorf(ix), y0f = floorf(iy);
            const float wx1 = ix - x0f,  wy1 = iy - y0f;
            const int x0 = (int)x0f, y0 = (int)y0f;
            const int x1 = x0 + 1,  y1 = y0 + 1;

            const float vx0 = (x0 >= 0 && x0 < WW) ? 1.0f : 0.0f;
            const float vx1 = (x1 >= 0 && x1 < WW) ? 1.0f : 0.0f;
            const float vy0 = (y0 >= 0 && y0 < HH) ? 1.0f : 0.0f;
            const float vy1 = (y1 >= 0 && y1 < HH) ? 1.0f : 0.0f;

            const int x0c = min(max(x0, 0), WW - 1);
            const int x1c = min(max(x1, 0), WW - 1);
            const int y0c = min(max(y0, 0), HH - 1);
            const int y1c = min(max(y1, 0), HH - 1);

            const float w00 = (1.0f - wy1) * (1.0f - wx1) * vy0 * vx0;
            const float w01 = (1.0f - wy1) * wx1          * vy0 * vx1;
            const float w10 = wy1          * (1.0f - wx1) * vy1 * vx0;
            const float w11 = wy1          * wx1          * vy1 * vx1;

            const int o00 = y0c * WW + x0c, o01 = y0c * WW + x1c;
            const int o10 = y1c * WW + x0c, o11 = y1c * WW + x1c;
            const int ob = oy * WW + ox;
            #pragma unroll
            for (int c = 0; c < CC; ++c) {
                const float* pc = imb + (long)c * plane;
                const float v = w00 * pc[o00] + w01 * pc[o01]
                              + w10 * pc[o10] + w11 * pc[o11];
                __builtin_nontemporal_store(v, &outb[(long)c * plane + ob]);
            }
        }
    }
}

extern "C" void kernel_launch(void* const* d_in, const int* in_sizes, int n_in,
                              void* d_out, int out_size, void* d_ws, size_t ws_size,
                              hipStream_t stream) {
    const float* img   = (const float*)d_in[0];
    const float* rot   = (const float*)d_in[1];
    const float* trans = (const float*)d_in[2];
    const float* scale = (const float*)d_in[3];
    float* out = (float*)d_out;
    float* ws  = (float*)d_ws;

    warp_setup<<<dim3(BB), 256, 0, stream>>>(rot, trans, scale, ws);
    warp_tiled<<<dim3(BB * 256), 512, 0, stream>>>(img, ws, out);
}

// Round 7
// 76.903 us; speedup vs baseline: 4.2212x; 1.0101x over previous
//
#include <hip/hip_runtime.h>
#include <stdint.h>

#define BB 64
#define CC 3
#define HH 512
#define WW 512
#define TILE 32
#define MAXBH 48
#define MAXBW 52
#define RS 58   // pixel-slot row stride: 58*4 dwords per row -> +2 bank-group phase/row

typedef float f32x2 __attribute__((ext_vector_type(2)));
typedef float f32x4 __attribute__((ext_vector_type(4)));

__device__ __forceinline__ void pix2in(float x, float y,
                                       float cs, float sn, float tx, float ty,
                                       float& ix, float& iy)
{
    float gx = (2.0f * x + 1.0f) * (1.0f / (float)WW) - 1.0f;
    float gy = (2.0f * y + 1.0f) * (1.0f / (float)HH) - 1.0f;
    float gxt = cs * gx - sn * gy + tx;
    float gyt = sn * gx + cs * gy + ty;
    ix = ((gxt + 1.0f) * (float)WW - 1.0f) * 0.5f;
    iy = ((gyt + 1.0f) * (float)HH - 1.0f) * 0.5f;
}

// ws layout: float prm[64*4] (cs,sn,tx,ty per batch), then uint32 desc[16384]
__global__ __launch_bounds__(256) void warp_setup(
    const float* __restrict__ rot, const float* __restrict__ trans,
    const float* __restrict__ scale, float* __restrict__ ws)
{
    const int i = blockIdx.x * 256 + threadIdx.x;   // 0..16383 = b*256+t
    const int b = i >> 8, t = i & 255;
    const float r = rot[b];
    const float inv_s = 1.0f / scale[b];
    const float cs = cosf(r) * inv_s;
    const float sn = sinf(r) * inv_s;
    const float tx = trans[2 * b], ty = trans[2 * b + 1];
    if (t == 0)
        reinterpret_cast<float4*>(ws)[b] = make_float4(cs, sn, tx, ty);

    const int oy0 = (t >> 4) * TILE;
    const int ox0 = (t & 15) * TILE;
    float ixa, iya, ixb, iyb, ixc, iyc, ixd, iyd;
    pix2in((float)ox0,              (float)oy0,              cs, sn, tx, ty, ixa, iya);
    pix2in((float)(ox0 + TILE - 1), (float)oy0,              cs, sn, tx, ty, ixb, iyb);
    pix2in((float)ox0,              (float)(oy0 + TILE - 1), cs, sn, tx, ty, ixc, iyc);
    pix2in((float)(ox0 + TILE - 1), (float)(oy0 + TILE - 1), cs, sn, tx, ty, ixd, iyd);
    const float minix = fminf(fminf(ixa, ixb), fminf(ixc, ixd));
    const float maxix = fmaxf(fmaxf(ixa, ixb), fmaxf(ixc, ixd));
    const float miniy = fminf(fminf(iya, iyb), fminf(iyc, iyd));
    const float maxiy = fmaxf(fmaxf(iya, iyb), fmaxf(iyc, iyd));
    const int bx0 = (int)floorf(minix) - 1;
    const int bx1 = (int)floorf(maxix) + 2;
    const int by0 = (int)floorf(miniy) - 1;
    const int by1 = (int)floorf(maxiy) + 2;
    int bx0c = bx0 & ~3;
    const int bw = bx1 - bx0c + 1;
    const int bh = by1 - by0 + 1;

    const uint32_t fit      = (bw <= MAXBW && bh <= MAXBH) ? 1u : 0u;
    const uint32_t interior = (bx0c >= 0 && bx1 < WW && by0 >= 0 && by1 < HH) ? 1u : 0u;
    const int bx0s = min(max(bx0c, -2048), 2047);
    const int by0s = min(max(by0,  -2048), 2047);
    const int bhs  = min(bh, 63);
    const uint32_t desc = ((uint32_t)bx0s & 0xFFFu)
                        | (((uint32_t)by0s & 0xFFFu) << 12)
                        | ((uint32_t)bhs << 24)
                        | (fit << 30) | (interior << 31);
    reinterpret_cast<uint32_t*>(ws)[256 + i] = desc;
}

template <bool INTERIOR>
__device__ __forceinline__ void compute_store(
    const f32x4 (*lds)[RS], float* __restrict__ outb,
    int tid, int ox0, int oy0, int bx0c, int by0,
    float cs, float sn, float tpx, float tpy, long plane)
{
    const int row = tid >> 4;            // 0..31
    const int xp  = (tid & 15) * 2;      // 0,2,...,30
    const int oy  = oy0 + row;
    const int oxb = ox0 + xp;

    float ix0, iy0;
    pix2in((float)oxb, (float)oy, cs, sn, tpx, tpy, ix0, iy0);

    f32x4 acc0, acc1;
    #pragma unroll
    for (int e = 0; e < 2; ++e) {
        const float ix = fmaf((float)e, cs, ix0);   // affine: +cs per output x
        const float iy = fmaf((float)e, sn, iy0);
        const float x0f = floorf(ix), y0f = floorf(iy);
        const float wx1 = ix - x0f,  wy1 = iy - y0f;
        const float wx0 = 1.0f - wx1, wy0 = 1.0f - wy1;
        const int x0 = (int)x0f, y0 = (int)y0f;

        float w00 = wy0 * wx0, w01 = wy0 * wx1, w10 = wy1 * wx0, w11 = wy1 * wx1;
        if (!INTERIOR) {
            const int x1 = x0 + 1, y1 = y0 + 1;
            const float vx0 = (x0 >= 0 && x0 < WW) ? 1.0f : 0.0f;
            const float vx1 = (x1 >= 0 && x1 < WW) ? 1.0f : 0.0f;
            const float vy0 = (y0 >= 0 && y0 < HH) ? 1.0f : 0.0f;
            const float vy1 = (y1 >= 0 && y1 < HH) ? 1.0f : 0.0f;
            w00 *= vy0 * vx0; w01 *= vy0 * vx1; w10 *= vy1 * vx0; w11 *= vy1 * vx1;
        }

        const int lx0 = x0 - bx0c;             // margin guarantees [1, bw-2]
        const int lx1 = lx0 + 1;
        const int ly0 = y0 - by0;
        const int s0  = lx0 ^ ((lx0 >> 2) & 7);
        const int s1  = lx1 ^ ((lx1 >> 2) & 7);

        const f32x4 p00 = lds[ly0][s0];
        const f32x4 p01 = lds[ly0][s1];
        const f32x4 p10 = lds[ly0 + 1][s0];    // same vaddr, offset:RS*16 imm
        const f32x4 p11 = lds[ly0 + 1][s1];

        const f32x4 r4 = w00 * p00 + w01 * p01 + w10 * p10 + w11 * p11;
        if (e == 0) acc0 = r4; else acc1 = r4;
    }
    const long ob = (long)oy * WW + oxb;
    const f32x2 o0 = {acc0.x, acc1.x};
    const f32x2 o1 = {acc0.y, acc1.y};
    const f32x2 o2 = {acc0.z, acc1.z};
    __builtin_nontemporal_store(o0, reinterpret_cast<f32x2*>(outb + ob));
    __builtin_nontemporal_store(o1, reinterpret_cast<f32x2*>(outb + plane + ob));
    __builtin_nontemporal_store(o2, reinterpret_cast<f32x2*>(outb + 2 * plane + ob));
}

__global__ __launch_bounds__(512) void warp_tiled(
    const float* __restrict__ img, const float* __restrict__ ws,
    float* __restrict__ out)
{
    __shared__ f32x4 lds[MAXBH][RS];     // 44.5 KB: one 16B pixel-vector per input px

    // XCD chunk swizzle: each XCD owns 8 whole batches
    const int g   = blockIdx.x;
    const int swz = (g & 7) * ((BB * 256) / 8) + (g >> 3);
    const int b   = swz >> 8;
    const int t   = swz & 255;
    const int oy0 = (t >> 4) * TILE;
    const int ox0 = (t & 15) * TILE;

    const float4 p = reinterpret_cast<const float4*>(ws)[b];
    const float cs = p.x, sn = p.y, tpx = p.z, tpy = p.w;
    const uint32_t desc = reinterpret_cast<const uint32_t*>(ws)[256 + swz];
    const int  bx0c     = ((int)(desc << 20)) >> 20;
    const int  by0      = ((int)(desc << 8))  >> 20;
    const int  bh       = (desc >> 24) & 63;
    const bool fit      = (desc >> 30) & 1;
    const bool interior = (desc >> 31) & 1;

    const long plane = (long)HH * WW;
    const float* imb = img + (long)b * CC * plane;
    float* outb      = out + (long)b * CC * plane;
    const int tid = threadIdx.x;

    if (fit) {
        const int q  = tid >> 4;          // 0..31 row group
        const int ql = tid & 15;          // 13 active lanes cover 52 cols
        if (ql < 13) {
            const int sb = (ql * 4) ^ (ql & 7);   // slot(4*ql+k) == sb ^ k
            if (interior && (bx0c + 51 < WW)) {
                // rows in [0,H), cols [bx0c, bx0c+51] in-row: unchecked float4 loads
                for (int r = q; r < bh; r += 32) {
                    const float* pr = imb + (long)(by0 + r) * WW + (bx0c + ql * 4);
                    const float4 a  = *reinterpret_cast<const float4*>(pr);
                    const float4 bv = *reinterpret_cast<const float4*>(pr + plane);
                    const float4 cv = *reinterpret_cast<const float4*>(pr + 2 * plane);
                    f32x4* lrow = lds[r];
                    lrow[sb ^ 0] = f32x4{a.x, bv.x, cv.x, 0.f};
                    lrow[sb ^ 1] = f32x4{a.y, bv.y, cv.y, 0.f};
                    lrow[sb ^ 2] = f32x4{a.z, bv.z, cv.z, 0.f};
                    lrow[sb ^ 3] = f32x4{a.w, bv.w, cv.w, 0.f};
                }
            } else {
                for (int r = q; r < bh; r += 32) {
                    const int grow = by0 + r;
                    const bool rowok = (grow >= 0) && (grow < HH);
                    const float* pr = imb + (long)grow * WW;
                    f32x4* lrow = lds[r];
                    #pragma unroll
                    for (int k = 0; k < 4; ++k) {
                        const int gcol = bx0c + ql * 4 + k;
                        f32x4 pv = {0.f, 0.f, 0.f, 0.f};
                        if (rowok && gcol >= 0 && gcol < WW) {
                            pv.x = pr[gcol];
                            pv.y = pr[(long)gcol + plane];
                            pv.z = pr[(long)gcol + 2 * plane];
                        }
                        lrow[sb ^ k] = pv;
                    }
                }
            }
        }
        __syncthreads();

        if (interior)
            compute_store<true >(lds, outb, tid, ox0, oy0, bx0c, by0, cs, sn, tpx, tpy, plane);
        else
            compute_store<false>(lds, outb, tid, ox0, oy0, bx0c, by0, cs, sn, tpx, tpy, plane);
    } else {
        // ---- fallback: direct global gather (never taken for scale=1) ----
        #pragma unroll
        for (int k = 0; k < 2; ++k) {
            const int pidx = tid + k * 512;
            const int py = pidx >> 5;
            const int px = pidx & 31;
            const int ox = ox0 + px, oy = oy0 + py;

            float ix, iy;
            pix2in((float)ox, (float)oy, cs, sn, tpx, tpy, ix, iy);
            const float x0f = floorf(ix), y0f = floorf(iy);
            const float wx1 = ix - x0f,  wy1 = iy - y0f;
            const int x0 = (int)x0f, y0 = (int)y0f;
            const int x1 = x0 + 1,  y1 = y0 + 1;

            const float vx0 = (x0 >= 0 && x0 < WW) ? 1.0f : 0.0f;
            const float vx1 = (x1 >= 0 && x1 < WW) ? 1.0f : 0.0f;
            const float vy0 = (y0 >= 0 && y0 < HH) ? 1.0f : 0.0f;
            const float vy1 = (y1 >= 0 && y1 < HH) ? 1.0f : 0.0f;

            const int x0c = min(max(x0, 0), WW - 1);
            const int x1c = min(max(x1, 0), WW - 1);
            const int y0c = min(max(y0, 0), HH - 1);
            const int y1c = min(max(y1, 0), HH - 1);

            const float w00 = (1.0f - wy1) * (1.0f - wx1) * vy0 * vx0;
            const float w01 = (1.0f - wy1) * wx1          * vy0 * vx1;
            const float w10 = wy1          * (1.0f - wx1) * vy1 * vx0;
            const float w11 = wy1          * wx1          * vy1 * vx1;

            const int o00 = y0c * WW + x0c, o01 = y0c * WW + x1c;
            const int o10 = y1c * WW + x0c, o11 = y1c * WW + x1c;
            const int ob = oy * WW + ox;
            #pragma unroll
            for (int c = 0; c < CC; ++c) {
                const float* pc = imb + (long)c * plane;
                const float v = w00 * pc[o00] + w01 * pc[o01]
                              + w10 * pc[o10] + w11 * pc[o11];
                __builtin_nontemporal_store(v, &outb[(long)c * plane + ob]);
            }
        }
    }
}

extern "C" void kernel_launch(void* const* d_in, const int* in_sizes, int n_in,
                              void* d_out, int out_size, void* d_ws, size_t ws_size,
                              hipStream_t stream) {
    const float* img   = (const float*)d_in[0];
    const float* rot   = (const float*)d_in[1];
    const float* trans = (const float*)d_in[2];
    const float* scale = (const float*)d_in[3];
    float* out = (float*)d_out;
    float* ws  = (float*)d_ws;

    warp_setup<<<dim3(BB), 256, 0, stream>>>(rot, trans, scale, ws);
    warp_tiled<<<dim3(BB * 256), 512, 0, stream>>>(img, ws, out);
}

// Round 8
// 72.128 us; speedup vs baseline: 4.5006x; 1.0662x over previous
//
#include <hip/hip_runtime.h>
#include <stdint.h>

#define BB 64
#define CC 3
#define HH 512
#define WW 512
#define TILE 32
#define MAXBH 48
#define MAXBW 52
#define PST 54   // pairs row stride (f32x2): 432B/row = 108 dwords = +12 bank phase
#define CST 56   // c2 row stride (float): 224B/row -> 16B-aligned rows, +24 bank phase

typedef float f32x2 __attribute__((ext_vector_type(2)));
typedef float f32x4 __attribute__((ext_vector_type(4)));

__device__ __forceinline__ void pix2in(float x, float y,
                                       float cs, float sn, float tx, float ty,
                                       float& ix, float& iy)
{
    float gx = (2.0f * x + 1.0f) * (1.0f / (float)WW) - 1.0f;
    float gy = (2.0f * y + 1.0f) * (1.0f / (float)HH) - 1.0f;
    float gxt = cs * gx - sn * gy + tx;
    float gyt = sn * gx + cs * gy + ty;
    ix = ((gxt + 1.0f) * (float)WW - 1.0f) * 0.5f;
    iy = ((gyt + 1.0f) * (float)HH - 1.0f) * 0.5f;
}

// ws layout: float prm[64*4] (cs,sn,tx,ty per batch), then uint32 desc[16384]
__global__ __launch_bounds__(256) void warp_setup(
    const float* __restrict__ rot, const float* __restrict__ trans,
    const float* __restrict__ scale, float* __restrict__ ws)
{
    const int i = blockIdx.x * 256 + threadIdx.x;   // 0..16383 = b*256+t
    const int b = i >> 8, t = i & 255;
    const float r = rot[b];
    const float inv_s = 1.0f / scale[b];
    const float cs = cosf(r) * inv_s;
    const float sn = sinf(r) * inv_s;
    const float tx = trans[2 * b], ty = trans[2 * b + 1];
    if (t == 0)
        reinterpret_cast<float4*>(ws)[b] = make_float4(cs, sn, tx, ty);

    const int oy0 = (t >> 4) * TILE;
    const int ox0 = (t & 15) * TILE;
    float ixa, iya, ixb, iyb, ixc, iyc, ixd, iyd;
    pix2in((float)ox0,              (float)oy0,              cs, sn, tx, ty, ixa, iya);
    pix2in((float)(ox0 + TILE - 1), (float)oy0,              cs, sn, tx, ty, ixb, iyb);
    pix2in((float)ox0,              (float)(oy0 + TILE - 1), cs, sn, tx, ty, ixc, iyc);
    pix2in((float)(ox0 + TILE - 1), (float)(oy0 + TILE - 1), cs, sn, tx, ty, ixd, iyd);
    const float minix = fminf(fminf(ixa, ixb), fminf(ixc, ixd));
    const float maxix = fmaxf(fmaxf(ixa, ixb), fmaxf(ixc, ixd));
    const float miniy = fminf(fminf(iya, iyb), fminf(iyc, iyd));
    const float maxiy = fmaxf(fmaxf(iya, iyb), fmaxf(iyc, iyd));
    const int bx0 = (int)floorf(minix) - 1;
    const int bx1 = (int)floorf(maxix) + 2;
    const int by0 = (int)floorf(miniy) - 1;
    const int by1 = (int)floorf(maxiy) + 2;
    int bx0c = bx0 & ~3;
    const int bw = bx1 - bx0c + 1;
    const int bh = by1 - by0 + 1;

    const uint32_t fit      = (bw <= MAXBW && bh <= MAXBH) ? 1u : 0u;
    const uint32_t interior = (bx0c >= 0 && bx1 < WW && by0 >= 0 && by1 < HH) ? 1u : 0u;
    const int bx0s = min(max(bx0c, -2048), 2047);
    const int by0s = min(max(by0,  -2048), 2047);
    const int bhs  = min(bh, 63);
    const uint32_t desc = ((uint32_t)bx0s & 0xFFFu)
                        | (((uint32_t)by0s & 0xFFFu) << 12)
                        | ((uint32_t)bhs << 24)
                        | (fit << 30) | (interior << 31);
    reinterpret_cast<uint32_t*>(ws)[256 + i] = desc;
}

template <bool INTERIOR>
__device__ __forceinline__ void compute_store(
    const f32x2 (*pairs)[PST], const float (*c2a)[CST], float* __restrict__ outb,
    int tid, int ox0, int oy0, int bx0c, int by0,
    float cs, float sn, float tpx, float tpy, long plane)
{
    const int row = tid >> 4;            // 0..31
    const int xp  = (tid & 15) * 2;      // 0,2,...,30
    const int oy  = oy0 + row;
    const int oxb = ox0 + xp;

    float ix0, iy0;
    pix2in((float)oxb, (float)oy, cs, sn, tpx, tpy, ix0, iy0);

    f32x2 r2[2];
    float rc[2];
    #pragma unroll
    for (int e = 0; e < 2; ++e) {
        const float ix = fmaf((float)e, cs, ix0);   // affine: +cs per output x
        const float iy = fmaf((float)e, sn, iy0);
        const float x0f = floorf(ix), y0f = floorf(iy);
        const float wx1 = ix - x0f,  wy1 = iy - y0f;
        const float wx0 = 1.0f - wx1, wy0 = 1.0f - wy1;
        const int x0 = (int)x0f, y0 = (int)y0f;

        float w00 = wy0 * wx0, w01 = wy0 * wx1, w10 = wy1 * wx0, w11 = wy1 * wx1;
        if (!INTERIOR) {
            const int x1 = x0 + 1, y1 = y0 + 1;
            const float vx0 = (x0 >= 0 && x0 < WW) ? 1.0f : 0.0f;
            const float vx1 = (x1 >= 0 && x1 < WW) ? 1.0f : 0.0f;
            const float vy0 = (y0 >= 0 && y0 < HH) ? 1.0f : 0.0f;
            const float vy1 = (y1 >= 0 && y1 < HH) ? 1.0f : 0.0f;
            w00 *= vy0 * vx0; w01 *= vy0 * vx1; w10 *= vy1 * vx0; w11 *= vy1 * vx1;
        }

        const int lx0 = x0 - bx0c;             // margin guarantees [1, bw-2]
        const int ly0 = y0 - by0;

        const f32x2 a00 = pairs[ly0][lx0];
        const f32x2 a01 = pairs[ly0][lx0 + 1];
        const f32x2 a10 = pairs[ly0 + 1][lx0];
        const f32x2 a11 = pairs[ly0 + 1][lx0 + 1];
        const float b00 = c2a[ly0][lx0];
        const float b01 = c2a[ly0][lx0 + 1];
        const float b10 = c2a[ly0 + 1][lx0];
        const float b11 = c2a[ly0 + 1][lx0 + 1];

        r2[e] = w00 * a00 + w01 * a01 + w10 * a10 + w11 * a11;
        rc[e] = w00 * b00 + w01 * b01 + w10 * b10 + w11 * b11;
    }
    const long ob = (long)oy * WW + oxb;
    const f32x2 o0 = {r2[0].x, r2[1].x};
    const f32x2 o1 = {r2[0].y, r2[1].y};
    const f32x2 o2 = {rc[0], rc[1]};
    __builtin_nontemporal_store(o0, reinterpret_cast<f32x2*>(outb + ob));
    __builtin_nontemporal_store(o1, reinterpret_cast<f32x2*>(outb + plane + ob));
    __builtin_nontemporal_store(o2, reinterpret_cast<f32x2*>(outb + 2 * plane + ob));
}

__global__ __launch_bounds__(512) void warp_tiled(
    const float* __restrict__ img, const float* __restrict__ ws,
    float* __restrict__ out)
{
    __shared__ f32x2 pairs[MAXBH][PST];            // 20.7 KB (c0,c1)
    __shared__ __align__(16) float c2a[MAXBH][CST]; // 10.8 KB (c2)

    // XCD chunk swizzle: each XCD owns 8 whole batches
    const int g   = blockIdx.x;
    const int swz = (g & 7) * ((BB * 256) / 8) + (g >> 3);
    const int b   = swz >> 8;
    const int t   = swz & 255;
    const int oy0 = (t >> 4) * TILE;
    const int ox0 = (t & 15) * TILE;

    const float4 p = reinterpret_cast<const float4*>(ws)[b];
    const float cs = p.x, sn = p.y, tpx = p.z, tpy = p.w;
    const uint32_t desc = reinterpret_cast<const uint32_t*>(ws)[256 + swz];
    const int  bx0c     = ((int)(desc << 20)) >> 20;
    const int  by0      = ((int)(desc << 8))  >> 20;
    const int  bh       = (desc >> 24) & 63;
    const bool fit      = (desc >> 30) & 1;
    const bool interior = (desc >> 31) & 1;

    const long plane = (long)HH * WW;
    const float* imb = img + (long)b * CC * plane;
    float* outb      = out + (long)b * CC * plane;
    const int tid = threadIdx.x;

    if (fit) {
        const int q  = tid >> 4;          // 0..31 row group
        const int ql = tid & 15;          // 13 active lanes cover 52 cols
        if (ql < 13) {
            const int xb = ql * 4;
            if (interior && (bx0c + 51 < WW)) {
                for (int r = q; r < bh; r += 32) {
                    const float* pr = imb + (long)(by0 + r) * WW + (bx0c + xb);
                    const float4 a  = *reinterpret_cast<const float4*>(pr);
                    const float4 bv = *reinterpret_cast<const float4*>(pr + plane);
                    const float4 cv = *reinterpret_cast<const float4*>(pr + 2 * plane);
                    f32x2* prow = &pairs[r][xb];
                    prow[0] = f32x2{a.x, bv.x};
                    prow[1] = f32x2{a.y, bv.y};
                    prow[2] = f32x2{a.z, bv.z};
                    prow[3] = f32x2{a.w, bv.w};
                    *reinterpret_cast<f32x4*>(&c2a[r][xb]) = f32x4{cv.x, cv.y, cv.z, cv.w};
                }
            } else {
                for (int r = q; r < bh; r += 32) {
                    const int grow = by0 + r;
                    const bool rowok = (grow >= 0) && (grow < HH);
                    const float* pr = imb + (long)grow * WW;
                    #pragma unroll
                    for (int k = 0; k < 4; ++k) {
                        const int gcol = bx0c + xb + k;
                        float vx = 0.f, vy = 0.f, vz = 0.f;
                        if (rowok && gcol >= 0 && gcol < WW) {
                            vx = pr[gcol];
                            vy = pr[(long)gcol + plane];
                            vz = pr[(long)gcol + 2 * plane];
                        }
                        pairs[r][xb + k] = f32x2{vx, vy};
                        c2a[r][xb + k] = vz;
                    }
                }
            }
        }
        __syncthreads();

        if (interior)
            compute_store<true >(pairs, c2a, outb, tid, ox0, oy0, bx0c, by0, cs, sn, tpx, tpy, plane);
        else
            compute_store<false>(pairs, c2a, outb, tid, ox0, oy0, bx0c, by0, cs, sn, tpx, tpy, plane);
    } else {
        // ---- fallback: direct global gather (never taken for scale=1) ----
        #pragma unroll
        for (int k = 0; k < 2; ++k) {
            const int pidx = tid + k * 512;
            const int py = pidx >> 5;
            const int px = pidx & 31;
            const int ox = ox0 + px, oy = oy0 + py;

            float ix, iy;
            pix2in((float)ox, (float)oy, cs, sn, tpx, tpy, ix, iy);
            const float x0f = floorf(ix), y0f = floorf(iy);
            const float wx1 = ix - x0f,  wy1 = iy - y0f;
            const int x0 = (int)x0f, y0 = (int)y0f;
            const int x1 = x0 + 1,  y1 = y0 + 1;

            const float vx0 = (x0 >= 0 && x0 < WW) ? 1.0f : 0.0f;
            const float vx1 = (x1 >= 0 && x1 < WW) ? 1.0f : 0.0f;
            const float vy0 = (y0 >= 0 && y0 < HH) ? 1.0f : 0.0f;
            const float vy1 = (y1 >= 0 && y1 < HH) ? 1.0f : 0.0f;

            const int x0c = min(max(x0, 0), WW - 1);
            const int x1c = min(max(x1, 0), WW - 1);
            const int y0c = min(max(y0, 0), HH - 1);
            const int y1c = min(max(y1, 0), HH - 1);

            const float w00 = (1.0f - wy1) * (1.0f - wx1) * vy0 * vx0;
            const float w01 = (1.0f - wy1) * wx1          * vy0 * vx1;
            const float w10 = wy1          * (1.0f - wx1) * vy1 * vx0;
            const float w11 = wy1          * wx1          * vy1 * vx1;

            const int o00 = y0c * WW + x0c, o01 = y0c * WW + x1c;
            const int o10 = y1c * WW + x0c, o11 = y1c * WW + x1c;
            const int ob = oy * WW + ox;
            #pragma unroll
            for (int c = 0; c < CC; ++c) {
                const float* pc = imb + (long)c * plane;
                const float v = w00 * pc[o00] + w01 * pc[o01]
                              + w10 * pc[o10] + w11 * pc[o11];
                __builtin_nontemporal_store(v, &outb[(long)c * plane + ob]);
            }
        }
    }
}

extern "C" void kernel_launch(void* const* d_in, const int* in_sizes, int n_in,
                              void* d_out, int out_size, void* d_ws, size_t ws_size,
                              hipStream_t stream) {
    const float* img   = (const float*)d_in[0];
    const float* rot   = (const float*)d_in[1];
    const float* trans = (const float*)d_in[2];
    const float* scale = (const float*)d_in[3];
    float* out = (float*)d_out;
    float* ws  = (float*)d_ws;

    warp_setup<<<dim3(BB), 256, 0, stream>>>(rot, trans, scale, ws);
    warp_tiled<<<dim3(BB * 256), 512, 0, stream>>>(img, ws, out);
}

// Round 9
// 70.925 us; speedup vs baseline: 4.5770x; 1.0170x over previous
//
#include <hip/hip_runtime.h>
#include <stdint.h>

#define BB 64
#define CC 3
#define HH 512
#define WW 512
#define TILE 32
#define MAXBH 48
#define MAXBW 52
#define PST 57   // pairs row stride in slots (8B): 456B/row = 114 dwords = +18 bank phase
#define CST 56   // c2 row stride (float): 224B/row -> 16B-aligned rows, +24 bank phase
// pairs slot map: physical p = x + (x>>4)  (pad every 16 slots)
// -> staging lane bases all distinct mod 32 banks: conflict-free writes (enumerated)

typedef float f32x2 __attribute__((ext_vector_type(2)));
typedef float f32x4 __attribute__((ext_vector_type(4)));

__device__ __forceinline__ void pix2in(float x, float y,
                                       float cs, float sn, float tx, float ty,
                                       float& ix, float& iy)
{
    float gx = (2.0f * x + 1.0f) * (1.0f / (float)WW) - 1.0f;
    float gy = (2.0f * y + 1.0f) * (1.0f / (float)HH) - 1.0f;
    float gxt = cs * gx - sn * gy + tx;
    float gyt = sn * gx + cs * gy + ty;
    ix = ((gxt + 1.0f) * (float)WW - 1.0f) * 0.5f;
    iy = ((gyt + 1.0f) * (float)HH - 1.0f) * 0.5f;
}

// ws layout: float prm[64*4] (cs,sn,tx,ty per batch), then uint32 desc[16384]
__global__ __launch_bounds__(256) void warp_setup(
    const float* __restrict__ rot, const float* __restrict__ trans,
    const float* __restrict__ scale, float* __restrict__ ws)
{
    const int i = blockIdx.x * 256 + threadIdx.x;   // 0..16383 = b*256+t
    const int b = i >> 8, t = i & 255;
    const float r = rot[b];
    const float inv_s = 1.0f / scale[b];
    const float cs = cosf(r) * inv_s;
    const float sn = sinf(r) * inv_s;
    const float tx = trans[2 * b], ty = trans[2 * b + 1];
    if (t == 0)
        reinterpret_cast<float4*>(ws)[b] = make_float4(cs, sn, tx, ty);

    const int oy0 = (t >> 4) * TILE;
    const int ox0 = (t & 15) * TILE;
    float ixa, iya, ixb, iyb, ixc, iyc, ixd, iyd;
    pix2in((float)ox0,              (float)oy0,              cs, sn, tx, ty, ixa, iya);
    pix2in((float)(ox0 + TILE - 1), (float)oy0,              cs, sn, tx, ty, ixb, iyb);
    pix2in((float)ox0,              (float)(oy0 + TILE - 1), cs, sn, tx, ty, ixc, iyc);
    pix2in((float)(ox0 + TILE - 1), (float)(oy0 + TILE - 1), cs, sn, tx, ty, ixd, iyd);
    const float minix = fminf(fminf(ixa, ixb), fminf(ixc, ixd));
    const float maxix = fmaxf(fmaxf(ixa, ixb), fmaxf(ixc, ixd));
    const float miniy = fminf(fminf(iya, iyb), fminf(iyc, iyd));
    const float maxiy = fmaxf(fmaxf(iya, iyb), fmaxf(iyc, iyd));
    const int bx0 = (int)floorf(minix) - 1;
    const int bx1 = (int)floorf(maxix) + 2;
    const int by0 = (int)floorf(miniy) - 1;
    const int by1 = (int)floorf(maxiy) + 2;
    int bx0c = bx0 & ~3;
    const int bw = bx1 - bx0c + 1;
    const int bh = by1 - by0 + 1;

    const uint32_t fit      = (bw <= MAXBW && bh <= MAXBH) ? 1u : 0u;
    const uint32_t interior = (bx0c >= 0 && bx1 < WW && by0 >= 0 && by1 < HH) ? 1u : 0u;
    const int bx0s = min(max(bx0c, -2048), 2047);
    const int by0s = min(max(by0,  -2048), 2047);
    const int bhs  = min(bh, 63);
    const uint32_t desc = ((uint32_t)bx0s & 0xFFFu)
                        | (((uint32_t)by0s & 0xFFFu) << 12)
                        | ((uint32_t)bhs << 24)
                        | (fit << 30) | (interior << 31);
    reinterpret_cast<uint32_t*>(ws)[256 + i] = desc;
}

template <bool INTERIOR>
__device__ __forceinline__ void compute_store(
    const f32x2 (*pairs)[PST], const float (*c2a)[CST], float* __restrict__ outb,
    int tid, int ox0, int oy0, int bx0c, int by0,
    float cs, float sn, float tpx, float tpy, long plane)
{
    const int row = tid >> 4;            // 0..31
    const int xp  = (tid & 15) * 2;      // 0,2,...,30
    const int oy  = oy0 + row;
    const int oxb = ox0 + xp;

    float ix0, iy0;
    pix2in((float)oxb, (float)oy, cs, sn, tpx, tpy, ix0, iy0);

    f32x2 r2[2];
    float rc[2];
    #pragma unroll
    for (int e = 0; e < 2; ++e) {
        const float ix = fmaf((float)e, cs, ix0);   // affine: +cs per output x
        const float iy = fmaf((float)e, sn, iy0);
        const float x0f = floorf(ix), y0f = floorf(iy);
        const float wx1 = ix - x0f,  wy1 = iy - y0f;
        const float wx0 = 1.0f - wx1, wy0 = 1.0f - wy1;
        const int x0 = (int)x0f, y0 = (int)y0f;

        float w00 = wy0 * wx0, w01 = wy0 * wx1, w10 = wy1 * wx0, w11 = wy1 * wx1;
        if (!INTERIOR) {
            const int x1 = x0 + 1, y1 = y0 + 1;
            const float vx0 = (x0 >= 0 && x0 < WW) ? 1.0f : 0.0f;
            const float vx1 = (x1 >= 0 && x1 < WW) ? 1.0f : 0.0f;
            const float vy0 = (y0 >= 0 && y0 < HH) ? 1.0f : 0.0f;
            const float vy1 = (y1 >= 0 && y1 < HH) ? 1.0f : 0.0f;
            w00 *= vy0 * vx0; w01 *= vy0 * vx1; w10 *= vy1 * vx0; w11 *= vy1 * vx1;
        }

        const int lx0 = x0 - bx0c;             // margin guarantees [1, bw-2]
        const int lx1 = lx0 + 1;
        const int ly0 = y0 - by0;
        const int p0  = lx0 + (lx0 >> 4);      // padded slot map
        const int p1  = lx1 + (lx1 >> 4);

        const f32x2 a00 = pairs[ly0][p0];
        const f32x2 a01 = pairs[ly0][p1];
        const f32x2 a10 = pairs[ly0 + 1][p0];
        const f32x2 a11 = pairs[ly0 + 1][p1];
        const float b00 = c2a[ly0][lx0];
        const float b01 = c2a[ly0][lx0 + 1];
        const float b10 = c2a[ly0 + 1][lx0];
        const float b11 = c2a[ly0 + 1][lx0 + 1];

        r2[e] = w00 * a00 + w01 * a01 + w10 * a10 + w11 * a11;
        rc[e] = w00 * b00 + w01 * b01 + w10 * b10 + w11 * b11;
    }
    const long ob = (long)oy * WW + oxb;
    const f32x2 o0 = {r2[0].x, r2[1].x};
    const f32x2 o1 = {r2[0].y, r2[1].y};
    const f32x2 o2 = {rc[0], rc[1]};
    __builtin_nontemporal_store(o0, reinterpret_cast<f32x2*>(outb + ob));
    __builtin_nontemporal_store(o1, reinterpret_cast<f32x2*>(outb + plane + ob));
    __builtin_nontemporal_store(o2, reinterpret_cast<f32x2*>(outb + 2 * plane + ob));
}

__global__ __launch_bounds__(512) void warp_tiled(
    const float* __restrict__ img, const float* __restrict__ ws,
    float* __restrict__ out)
{
    __shared__ f32x2 pairs[MAXBH][PST];             // 21.4 KB (c0,c1), padded-slot layout
    __shared__ __align__(16) float c2a[MAXBH][CST]; // 10.5 KB (c2)

    // XCD chunk swizzle: each XCD owns 8 whole batches
    const int g   = blockIdx.x;
    const int swz = (g & 7) * ((BB * 256) / 8) + (g >> 3);
    const int b   = swz >> 8;
    const int t   = swz & 255;
    const int oy0 = (t >> 4) * TILE;
    const int ox0 = (t & 15) * TILE;

    const float4 p = reinterpret_cast<const float4*>(ws)[b];
    const float cs = p.x, sn = p.y, tpx = p.z, tpy = p.w;
    const uint32_t desc = reinterpret_cast<const uint32_t*>(ws)[256 + swz];
    const int  bx0c     = ((int)(desc << 20)) >> 20;
    const int  by0      = ((int)(desc << 8))  >> 20;
    const int  bh       = (desc >> 24) & 63;
    const bool fit      = (desc >> 30) & 1;
    const bool interior = (desc >> 31) & 1;

    const long plane = (long)HH * WW;
    const float* imb = img + (long)b * CC * plane;
    float* outb      = out + (long)b * CC * plane;
    const int tid = threadIdx.x;

    if (fit) {
        const int q  = tid >> 4;          // 0..31 row group
        const int ql = tid & 15;          // 13 active lanes cover 52 cols
        if (ql < 13) {
            const int xb = ql * 4;                 // global col offset within bbox
            const int pb = xb + (ql >> 2);         // padded LDS slot base (contiguous 4)
            if (interior && (bx0c + 51 < WW)) {
                for (int r = q; r < bh; r += 32) {
                    const float* pr = imb + (long)(by0 + r) * WW + (bx0c + xb);
                    const float4 a  = *reinterpret_cast<const float4*>(pr);
                    const float4 bv = *reinterpret_cast<const float4*>(pr + plane);
                    const float4 cv = *reinterpret_cast<const float4*>(pr + 2 * plane);
                    f32x2* prow = &pairs[r][pb];
                    prow[0] = f32x2{a.x, bv.x};
                    prow[1] = f32x2{a.y, bv.y};
                    prow[2] = f32x2{a.z, bv.z};
                    prow[3] = f32x2{a.w, bv.w};
                    *reinterpret_cast<f32x4*>(&c2a[r][xb]) = f32x4{cv.x, cv.y, cv.z, cv.w};
                }
            } else {
                for (int r = q; r < bh; r += 32) {
                    const int grow = by0 + r;
                    const bool rowok = (grow >= 0) && (grow < HH);
                    const float* pr = imb + (long)grow * WW;
                    #pragma unroll
                    for (int k = 0; k < 4; ++k) {
                        const int gcol = bx0c + xb + k;
                        float vx = 0.f, vy = 0.f, vz = 0.f;
                        if (rowok && gcol >= 0 && gcol < WW) {
                            vx = pr[gcol];
                            vy = pr[(long)gcol + plane];
                            vz = pr[(long)gcol + 2 * plane];
                        }
                        pairs[r][pb + k] = f32x2{vx, vy};
                        c2a[r][xb + k] = vz;
                    }
                }
            }
        }
        __syncthreads();

        if (interior)
            compute_store<true >(pairs, c2a, outb, tid, ox0, oy0, bx0c, by0, cs, sn, tpx, tpy, plane);
        else
            compute_store<false>(pairs, c2a, outb, tid, ox0, oy0, bx0c, by0, cs, sn, tpx, tpy, plane);
    } else {
        // ---- fallback: direct global gather (never taken for scale=1) ----
        #pragma unroll
        for (int k = 0; k < 2; ++k) {
            const int pidx = tid + k * 512;
            const int py = pidx >> 5;
            const int px = pidx & 31;
            const int ox = ox0 + px, oy = oy0 + py;

            float ix, iy;
            pix2in((float)ox, (float)oy, cs, sn, tpx, tpy, ix, iy);
            const float x0f = floorf(ix), y0f = floorf(iy);
            const float wx1 = ix - x0f,  wy1 = iy - y0f;
            const int x0 = (int)x0f, y0 = (int)y0f;
            const int x1 = x0 + 1,  y1 = y0 + 1;

            const float vx0 = (x0 >= 0 && x0 < WW) ? 1.0f : 0.0f;
            const float vx1 = (x1 >= 0 && x1 < WW) ? 1.0f : 0.0f;
            const float vy0 = (y0 >= 0 && y0 < HH) ? 1.0f : 0.0f;
            const float vy1 = (y1 >= 0 && y1 < HH) ? 1.0f : 0.0f;

            const int x0c = min(max(x0, 0), WW - 1);
            const int x1c = min(max(x1, 0), WW - 1);
            const int y0c = min(max(y0, 0), HH - 1);
            const int y1c = min(max(y1, 0), HH - 1);

            const float w00 = (1.0f - wy1) * (1.0f - wx1) * vy0 * vx0;
            const float w01 = (1.0f - wy1) * wx1          * vy0 * vx1;
            const float w10 = wy1          * (1.0f - wx1) * vy1 * vx0;
            const float w11 = wy1          * wx1          * vy1 * vx1;

            const int o00 = y0c * WW + x0c, o01 = y0c * WW + x1c;
            const int o10 = y1c * WW + x0c, o11 = y1c * WW + x1c;
            const int ob = oy * WW + ox;
            #pragma unroll
            for (int c = 0; c < CC; ++c) {
                const float* pc = imb + (long)c * plane;
                const float v = w00 * pc[o00] + w01 * pc[o01]
                              + w10 * pc[o10] + w11 * pc[o11];
                __builtin_nontemporal_store(v, &outb[(long)c * plane + ob]);
            }
        }
    }
}

extern "C" void kernel_launch(void* const* d_in, const int* in_sizes, int n_in,
                              void* d_out, int out_size, void* d_ws, size_t ws_size,
                              hipStream_t stream) {
    const float* img   = (const float*)d_in[0];
    const float* rot   = (const float*)d_in[1];
    const float* trans = (const float*)d_in[2];
    const float* scale = (const float*)d_in[3];
    float* out = (float*)d_out;
    float* ws  = (float*)d_ws;

    warp_setup<<<dim3(BB), 256, 0, stream>>>(rot, trans, scale, ws);
    warp_tiled<<<dim3(BB * 256), 512, 0, stream>>>(img, ws, out);
}

// Round 11
// 67.680 us; speedup vs baseline: 4.7964x; 1.0479x over previous
//
#include <hip/hip_runtime.h>
#include <stdint.h>

#define BB 64
#define CC 3
#define HH 512
#define WW 512
#define TILE 32
#define MAXBH 48
#define MAXBW 52
#define PLST 52  // plane row stride (dwords): 16B-aligned rows, +20 bank phase/row

typedef float f32x2 __attribute__((ext_vector_type(2)));
typedef float f32x4 __attribute__((ext_vector_type(4)));

__device__ __forceinline__ void pix2in(float x, float y,
                                       float cs, float sn, float tx, float ty,
                                       float& ix, float& iy)
{
    float gx = (2.0f * x + 1.0f) * (1.0f / (float)WW) - 1.0f;
    float gy = (2.0f * y + 1.0f) * (1.0f / (float)HH) - 1.0f;
    float gxt = cs * gx - sn * gy + tx;
    float gyt = sn * gx + cs * gy + ty;
    ix = ((gxt + 1.0f) * (float)WW - 1.0f) * 0.5f;
    iy = ((gyt + 1.0f) * (float)HH - 1.0f) * 0.5f;
}

// ws layout: float prm[64*4] (cs,sn,tx,ty per batch), then uint32 desc[16384]
__global__ __launch_bounds__(256) void warp_setup(
    const float* __restrict__ rot, const float* __restrict__ trans,
    const float* __restrict__ scale, float* __restrict__ ws)
{
    const int i = blockIdx.x * 256 + threadIdx.x;   // 0..16383 = b*256+t
    const int b = i >> 8, t = i & 255;
    const float r = rot[b];
    const float inv_s = 1.0f / scale[b];
    const float cs = cosf(r) * inv_s;
    const float sn = sinf(r) * inv_s;
    const float tx = trans[2 * b], ty = trans[2 * b + 1];
    if (t == 0)
        reinterpret_cast<float4*>(ws)[b] = make_float4(cs, sn, tx, ty);

    const int oy0 = (t >> 4) * TILE;
    const int ox0 = (t & 15) * TILE;
    float ixa, iya, ixb, iyb, ixc, iyc, ixd, iyd;
    pix2in((float)ox0,              (float)oy0,              cs, sn, tx, ty, ixa, iya);
    pix2in((float)(ox0 + TILE - 1), (float)oy0,              cs, sn, tx, ty, ixb, iyb);
    pix2in((float)ox0,              (float)(oy0 + TILE - 1), cs, sn, tx, ty, ixc, iyc);
    pix2in((float)(ox0 + TILE - 1), (float)(oy0 + TILE - 1), cs, sn, tx, ty, ixd, iyd);
    const float minix = fminf(fminf(ixa, ixb), fminf(ixc, ixd));
    const float maxix = fmaxf(fmaxf(ixa, ixb), fmaxf(ixc, ixd));
    const float miniy = fminf(fminf(iya, iyb), fminf(iyc, iyd));
    const float maxiy = fmaxf(fmaxf(iya, iyb), fmaxf(iyc, iyd));
    const int bx0 = (int)floorf(minix) - 1;
    const int bx1 = (int)floorf(maxix) + 2;
    const int by0 = (int)floorf(miniy) - 1;
    const int by1 = (int)floorf(maxiy) + 2;
    int bx0c = bx0 & ~3;
    const int bw = bx1 - bx0c + 1;
    const int bh = by1 - by0 + 1;

    const uint32_t fit      = (bw <= MAXBW && bh <= MAXBH) ? 1u : 0u;
    const uint32_t interior = (bx0c >= 0 && bx1 < WW && by0 >= 0 && by1 < HH) ? 1u : 0u;
    const int bx0s = min(max(bx0c, -2048), 2047);
    const int by0s = min(max(by0,  -2048), 2047);
    const int bhs  = min(bh, 63);
    const uint32_t desc = ((uint32_t)bx0s & 0xFFFu)
                        | (((uint32_t)by0s & 0xFFFu) << 12)
                        | ((uint32_t)bhs << 24)
                        | (fit << 30) | (interior << 31);
    reinterpret_cast<uint32_t*>(ws)[256 + i] = desc;
}

template <bool INTERIOR>
__device__ __forceinline__ void compute_store(
    const float* __restrict__ pl, float* __restrict__ outb,
    int tid, int ox0, int oy0, int bx0c, int by0,
    float cs, float sn, float tpx, float tpy, long plane)
{
    const int row = tid >> 4;            // 0..31
    const int xp  = (tid & 15) * 2;      // 0,2,...,30
    const int oy  = oy0 + row;
    const int oxb = ox0 + xp;

    float ix0, iy0;
    pix2in((float)oxb, (float)oy, cs, sn, tpx, tpy, ix0, iy0);

    float r0[2], r1[2], r2[2];
    #pragma unroll
    for (int e = 0; e < 2; ++e) {
        const float ix = fmaf((float)e, cs, ix0);   // affine: +cs per output x
        const float iy = fmaf((float)e, sn, iy0);
        const float x0f = floorf(ix), y0f = floorf(iy);
        const float wx1 = ix - x0f,  wy1 = iy - y0f;
        const float wx0 = 1.0f - wx1, wy0 = 1.0f - wy1;
        const int x0 = (int)x0f, y0 = (int)y0f;

        float w00 = wy0 * wx0, w01 = wy0 * wx1, w10 = wy1 * wx0, w11 = wy1 * wx1;
        if (!INTERIOR) {
            const int x1 = x0 + 1, y1 = y0 + 1;
            const float vx0 = (x0 >= 0 && x0 < WW) ? 1.0f : 0.0f;
            const float vx1 = (x1 >= 0 && x1 < WW) ? 1.0f : 0.0f;
            const float vy0 = (y0 >= 0 && y0 < HH) ? 1.0f : 0.0f;
            const float vy1 = (y1 >= 0 && y1 < HH) ? 1.0f : 0.0f;
            w00 *= vy0 * vx0; w01 *= vy0 * vx1; w10 *= vy1 * vx0; w11 *= vy1 * vx1;
        }

        const int idx = (y0 - by0) * PLST + (x0 - bx0c);
        // single vaddr; channel planes + row-pair reachable via byte immediates
        const float* pb = pl + idx;
        #pragma unroll
        for (int c = 0; c < CC; ++c) {
            const float* pc = pb + c * (MAXBH * PLST);
            const float v00 = pc[0];
            const float v01 = pc[1];
            const float v10 = pc[PLST];
            const float v11 = pc[PLST + 1];
            const float v = w00 * v00 + w01 * v01 + w10 * v10 + w11 * v11;
            if (c == 0) r0[e] = v; else if (c == 1) r1[e] = v; else r2[e] = v;
        }
    }
    const long ob = (long)oy * WW + oxb;
    const f32x2 o0 = {r0[0], r0[1]};
    const f32x2 o1 = {r1[0], r1[1]};
    const f32x2 o2 = {r2[0], r2[1]};
    __builtin_nontemporal_store(o0, reinterpret_cast<f32x2*>(outb + ob));
    __builtin_nontemporal_store(o1, reinterpret_cast<f32x2*>(outb + plane + ob));
    __builtin_nontemporal_store(o2, reinterpret_cast<f32x2*>(outb + 2 * plane + ob));
}

__global__ __launch_bounds__(512) void warp_tiled(
    const float* __restrict__ img, const float* __restrict__ ws,
    float* __restrict__ out)
{
    __shared__ __align__(16) float pl[CC][MAXBH][PLST];   // 29.3 KB, 3 channel planes

    // XCD chunk swizzle: each XCD owns 8 whole batches
    const int g   = blockIdx.x;
    const int swz = (g & 7) * ((BB * 256) / 8) + (g >> 3);
    const int b   = swz >> 8;
    const int t   = swz & 255;
    const int oy0 = (t >> 4) * TILE;
    const int ox0 = (t & 15) * TILE;

    const float4 p = reinterpret_cast<const float4*>(ws)[b];
    const float cs = p.x, sn = p.y, tpx = p.z, tpy = p.w;
    const uint32_t desc = reinterpret_cast<const uint32_t*>(ws)[256 + swz];
    const int  bx0c     = ((int)(desc << 20)) >> 20;
    const int  by0      = ((int)(desc << 8))  >> 20;
    const int  bh       = (desc >> 24) & 63;
    const bool fit      = (desc >> 30) & 1;
    const bool interior = (desc >> 31) & 1;

    const long plane = (long)HH * WW;
    const float* imb = img + (long)b * CC * plane;
    float* outb      = out + (long)b * CC * plane;
    const int tid = threadIdx.x;

    if (fit) {
        const int q  = tid >> 4;          // 0..31 row group
        const int ql = tid & 15;          // 13 active lanes cover 52 cols
        if (ql < 13) {
            const int xb = ql * 4;        // col offset within bbox, 16B-aligned slot
            if (interior && (bx0c + 51 < WW)) {
                for (int r = q; r < bh; r += 32) {
                    const float* pr = imb + (long)(by0 + r) * WW + (bx0c + xb);
                    const f32x4 a = *reinterpret_cast<const f32x4*>(pr);
                    const f32x4 bv = *reinterpret_cast<const f32x4*>(pr + plane);
                    const f32x4 cv = *reinterpret_cast<const f32x4*>(pr + 2 * plane);
                    *reinterpret_cast<f32x4*>(&pl[0][r][xb]) = a;    // contiguous b128
                    *reinterpret_cast<f32x4*>(&pl[1][r][xb]) = bv;
                    *reinterpret_cast<f32x4*>(&pl[2][r][xb]) = cv;
                }
            } else {
                for (int r = q; r < bh; r += 32) {
                    const int grow = by0 + r;
                    const bool rowok = (grow >= 0) && (grow < HH);
                    const float* pr = imb + (long)grow * WW;
                    f32x4 a = {0.f, 0.f, 0.f, 0.f}, bv = a, cv = a;
                    #pragma unroll
                    for (int k = 0; k < 4; ++k) {
                        const int gcol = bx0c + xb + k;
                        if (rowok && gcol >= 0 && gcol < WW) {
                            a[k]  = pr[gcol];
                            bv[k] = pr[(long)gcol + plane];
                            cv[k] = pr[(long)gcol + 2 * plane];
                        }
                    }
                    *reinterpret_cast<f32x4*>(&pl[0][r][xb]) = a;
                    *reinterpret_cast<f32x4*>(&pl[1][r][xb]) = bv;
                    *reinterpret_cast<f32x4*>(&pl[2][r][xb]) = cv;
                }
            }
        }
        __syncthreads();

        if (interior)
            compute_store<true >(&pl[0][0][0], outb, tid, ox0, oy0, bx0c, by0, cs, sn, tpx, tpy, plane);
        else
            compute_store<false>(&pl[0][0][0], outb, tid, ox0, oy0, bx0c, by0, cs, sn, tpx, tpy, plane);
    } else {
        // ---- fallback: direct global gather (never taken for scale=1) ----
        #pragma unroll
        for (int k = 0; k < 2; ++k) {
            const int pidx = tid + k * 512;
            const int py = pidx >> 5;
            const int px = pidx & 31;
            const int ox = ox0 + px, oy = oy0 + py;

            float ix, iy;
            pix2in((float)ox, (float)oy, cs, sn, tpx, tpy, ix, iy);
            const float x0f = floorf(ix), y0f = floorf(iy);
            const float wx1 = ix - x0f,  wy1 = iy - y0f;
            const int x0 = (int)x0f, y0 = (int)y0f;
            const int x1 = x0 + 1,  y1 = y0 + 1;

            const float vx0 = (x0 >= 0 && x0 < WW) ? 1.0f : 0.0f;
            const float vx1 = (x1 >= 0 && x1 < WW) ? 1.0f : 0.0f;
            const float vy0 = (y0 >= 0 && y0 < HH) ? 1.0f : 0.0f;
            const float vy1 = (y1 >= 0 && y1 < HH) ? 1.0f : 0.0f;

            const int x0c = min(max(x0, 0), WW - 1);
            const int x1c = min(max(x1, 0), WW - 1);
            const int y0c = min(max(y0, 0), HH - 1);
            const int y1c = min(max(y1, 0), HH - 1);

            const float w00 = (1.0f - wy1) * (1.0f - wx1) * vy0 * vx0;
            const float w01 = (1.0f - wy1) * wx1          * vy0 * vx1;
            const float w10 = wy1          * (1.0f - wx1) * vy1 * vx0;
            const float w11 = wy1          * wx1          * vy1 * vx1;

            const int o00 = y0c * WW + x0c, o01 = y0c * WW + x1c;
            const int o10 = y1c * WW + x0c, o11 = y1c * WW + x1c;
            const int ob = oy * WW + ox;
            #pragma unroll
            for (int c = 0; c < CC; ++c) {
                const float* pc = imb + (long)c * plane;
                const float v = w00 * pc[o00] + w01 * pc[o01]
                              + w10 * pc[o10] + w11 * pc[o11];
                __builtin_nontemporal_store(v, &outb[(long)c * plane + ob]);
            }
        }
    }
}

extern "C" void kernel_launch(void* const* d_in, const int* in_sizes, int n_in,
                              void* d_out, int out_size, void* d_ws, size_t ws_size,
                              hipStream_t stream) {
    const float* img   = (const float*)d_in[0];
    const float* rot   = (const float*)d_in[1];
    const float* trans = (const float*)d_in[2];
    const float* scale = (const float*)d_in[3];
    float* out = (float*)d_out;
    float* ws  = (float*)d_ws;

    warp_setup<<<dim3(BB), 256, 0, stream>>>(rot, trans, scale, ws);
    warp_tiled<<<dim3(BB * 256), 512, 0, stream>>>(img, ws, out);
}